// Round 2
// baseline (13971.350 us; speedup 1.0000x reference)
//
#include <hip/hip_runtime.h>
#include <stdint.h>

// ---------------- problem dims (hard-coded from setup_inputs) ----------------
static constexpr int B      = 16;
static constexpr int N      = 128;
static constexpr int P      = 4064;     // 32*(128-1) kept pairs
static constexpr int MPOSE  = 64;
static constexpr int64_t BN = (int64_t)B * N;   // 2048
static constexpr int64_t BP = (int64_t)B * P;   // 65024 (multiple of 64)

#define TWO_PI 6.283185307179586f
#define QSCALE 0.17677669529663687f  /* 1/sqrt(32) */

__device__ __forceinline__ void pair_xy(int p, int& x, int& y) {
    x = p / 127;
    int r = p - x * 127;
    y = (r < x) ? r : r + 1;
}

// ---------------- generic tiled SGEMM: C = act(A(+A2) @ W + bias) ----------------
// 64x64 tile, BK=16, 256 threads, 4x4 micro-tile. Requires M%64==0, Ncols%64==0.
template <bool RELU_OUT, bool ADD_C, bool RELU_A>
__global__ __launch_bounds__(256) void gemm_k(
    const float* __restrict__ A, const float* __restrict__ A2, int lda,
    const float* __restrict__ W, int ldw,
    const float* __restrict__ bias,
    float* __restrict__ C, int ldc,
    int M, int Ncols, int K)
{
    __shared__ float As[16][65];
    __shared__ float Ws[16][65];
    const int tid = threadIdx.x;
    const int tx = tid & 15, ty = tid >> 4;
    const int row0 = blockIdx.y * 64, col0 = blockIdx.x * 64;
    float acc[4][4] = {};

    for (int k0 = 0; k0 < K; k0 += 16) {
#pragma unroll
        for (int i = 0; i < 4; ++i) {
            int idx = tid + i * 256;
            int r = idx >> 4, c = idx & 15;
            int gk = k0 + c;
            float a = 0.f;
            if (gk < K) {
                int64_t off = (int64_t)(row0 + r) * lda + gk;
                a = A[off];
                if (A2) a += A2[off];
                if (RELU_A) a = fmaxf(a, 0.f);
            }
            As[c][r] = a;
        }
#pragma unroll
        for (int i = 0; i < 4; ++i) {
            int idx = tid + i * 256;
            int r = idx >> 6, c = idx & 63;
            int gk = k0 + r;
            Ws[r][c] = (gk < K) ? W[(int64_t)gk * ldw + col0 + c] : 0.f;
        }
        __syncthreads();
#pragma unroll
        for (int kk = 0; kk < 16; ++kk) {
            float av[4], wv[4];
#pragma unroll
            for (int i = 0; i < 4; ++i) av[i] = As[kk][ty * 4 + i];
#pragma unroll
            for (int j = 0; j < 4; ++j) wv[j] = Ws[kk][tx * 4 + j];
#pragma unroll
            for (int i = 0; i < 4; ++i)
#pragma unroll
                for (int j = 0; j < 4; ++j) acc[i][j] += av[i] * wv[j];
        }
        __syncthreads();
    }
#pragma unroll
    for (int i = 0; i < 4; ++i) {
        int r = row0 + ty * 4 + i;
#pragma unroll
        for (int j = 0; j < 4; ++j) {
            int c = col0 + tx * 4 + j;
            float v = acc[i][j];
            if (bias) v += bias[c];
            if (ADD_C) v += C[(int64_t)r * ldc + c];
            if (RELU_OUT) v = fmaxf(v, 0.f);
            C[(int64_t)r * ldc + c] = v;
        }
    }
}

static void gemm(hipStream_t st,
                 const float* A, const float* A2, int lda,
                 const float* W, int ldw, const float* bias,
                 float* C, int ldc, int M, int Ncols, int K,
                 bool reluOut, bool addC, bool reluA)
{
    dim3 g(Ncols / 64, M / 64), b(256);
    if (!reluOut && !addC && !reluA)
        gemm_k<false,false,false><<<g,b,0,st>>>(A,A2,lda,W,ldw,bias,C,ldc,M,Ncols,K);
    else if (reluOut && !addC && !reluA)
        gemm_k<true,false,false><<<g,b,0,st>>>(A,A2,lda,W,ldw,bias,C,ldc,M,Ncols,K);
    else if (!reluOut && addC && !reluA)
        gemm_k<false,true,false><<<g,b,0,st>>>(A,A2,lda,W,ldw,bias,C,ldc,M,Ncols,K);
    else if (!reluOut && !addC && reluA)
        gemm_k<false,false,true><<<g,b,0,st>>>(A,A2,lda,W,ldw,bias,C,ldc,M,Ncols,K);
    else if (reluOut && addC && reluA)
        gemm_k<true,true,true><<<g,b,0,st>>>(A,A2,lda,W,ldw,bias,C,ldc,M,Ncols,K);
    else
        gemm_k<true,true,false><<<g,b,0,st>>>(A,A2,lda,W,ldw,bias,C,ldc,M,Ncols,K);
}

// ---------------- LayerNorm (D=256), optional residual, in-place safe ----------------
__global__ __launch_bounds__(256) void ln_k(
    float* __restrict__ out, const float* __restrict__ x, const float* __restrict__ res,
    const float* __restrict__ g, const float* __restrict__ be, int rows)
{
    int wave = threadIdx.x >> 6, lane = threadIdx.x & 63;
    int row = blockIdx.x * 4 + wave;
    if (row >= rows) return;
    int64_t base = (int64_t)row * 256 + lane * 4;
    float4 v = *(const float4*)(x + base);
    if (res) {
        float4 r = *(const float4*)(res + base);
        v.x += r.x; v.y += r.y; v.z += r.z; v.w += r.w;
    }
    float s  = v.x + v.y + v.z + v.w;
    float sq = v.x*v.x + v.y*v.y + v.z*v.z + v.w*v.w;
#pragma unroll
    for (int off = 1; off < 64; off <<= 1) {
        s  += __shfl_xor(s, off);
        sq += __shfl_xor(sq, off);
    }
    float m = s * (1.f/256.f);
    float var = sq * (1.f/256.f) - m * m;
    float inv = rsqrtf(var + 1e-5f);
    int c = lane * 4;
    float4 gg = *(const float4*)(g + c);
    float4 bb = *(const float4*)(be + c);
    float4 o;
    o.x = (v.x - m) * inv * gg.x + bb.x;
    o.y = (v.y - m) * inv * gg.y + bb.y;
    o.z = (v.z - m) * inv * gg.z + bb.z;
    o.w = (v.w - m) * inv * gg.w + bb.w;
    *(float4*)(out + base) = o;
}

// ---------------- line: mean over 8x8, then small proj (16x2048x256) ----------------
__global__ __launch_bounds__(256) void line_mean_k(const float* __restrict__ line, float* __restrict__ lm)
{
    int wave = threadIdx.x >> 6, lane = threadIdx.x & 63;
    int bc = blockIdx.x * 4 + wave;           // 0 .. B*2048-1
    float v = line[(int64_t)bc * 64 + lane];
#pragma unroll
    for (int off = 1; off < 64; off <<= 1) v += __shfl_xor(v, off);
    if (lane == 0) lm[bc] = v * (1.f/64.f);
}

__global__ __launch_bounds__(256) void line_proj_k(
    const float* __restrict__ lm, const float* __restrict__ lw,
    const float* __restrict__ lb, float* __restrict__ lf)
{
    int b = blockIdx.x, j = threadIdx.x;
    float acc = lb[j];
    const float* lmb = lm + (int64_t)b * 2048;
    for (int c = 0; c < 2048; ++c) acc += lmb[c] * lw[(int64_t)c * 256 + j];
    lf[b * 256 + j] = acc;
}

// ---------------- sinusoidal box PE: (B,N,512) = [pe(cy),pe(cx),pe(h),pe(w)] ----------------
__global__ __launch_bounds__(512) void boxpe_k(
    const float* __restrict__ boxes, const float* __restrict__ sizes, float* __restrict__ boxpe)
{
    int row = blockIdx.x;          // b*N + n
    int b = row >> 7;
    int i = threadIdx.x;           // 0..511
    const float* bx = boxes + (int64_t)row * 4;
    float h = sizes[b * 2 + 0], w = sizes[b * 2 + 1];
    float x0 = bx[0] / w, y0 = bx[1] / h, x1 = bx[2] / w, y1 = bx[3] / h;
    int seg = i >> 7, j = i & 127, k = j >> 1;
    float val;
    switch (seg) {
        case 0: val = (y0 + y1) * 0.5f; break;   // cy
        case 1: val = (x0 + x1) * 0.5f; break;   // cx
        case 2: val = (y1 - y0); break;          // h
        default: val = (x1 - x0); break;         // w
    }
    float dimt = powf(20.f, (float)k * (1.f/64.f));
    float arg = val * TWO_PI / dimt;
    boxpe[(int64_t)row * 512 + i] = (j & 1) ? cosf(arg) : sinf(arg);
}

// ---------------- spatial 36 features for a chunk of kept pairs ----------------
__global__ __launch_bounds__(256) void f36_k(
    const float* __restrict__ boxes, const float* __restrict__ sizes,
    float* __restrict__ f36, int chunk0, int cnt)
{
    int li = blockIdx.x * 256 + threadIdx.x;
    if (li >= cnt) return;
    int gp = chunk0 + li;
    int b = gp / P, p = gp - b * P;
    int xi, yi; pair_xy(p, xi, yi);
    const float* b1 = boxes + ((int64_t)b * N + xi) * 4;
    const float* b2 = boxes + ((int64_t)b * N + yi) * 4;
    float h = sizes[b * 2 + 0], w = sizes[b * 2 + 1];
    float c1x = (b1[0] + b1[2]) * 0.5f, c1y = (b1[1] + b1[3]) * 0.5f;
    float c2x = (b2[0] + b2[2]) * 0.5f, c2y = (b2[1] + b2[3]) * 0.5f;
    float w1 = b1[2] - b1[0], h1 = b1[3] - b1[1];
    float w2 = b2[2] - b2[0], h2 = b2[3] - b2[1];
    float a1 = w1 * h1, a2 = w2 * h2;
    float dx = fabsf(c2x - c1x) / (w1 + 1e-6f);
    float dy = fabsf(c2y - c1y) / (h1 + 1e-6f);
    float ix = fmaxf(fminf(b1[2], b2[2]) - fmaxf(b1[0], b2[0]), 0.f);
    float iy = fmaxf(fminf(b1[3], b2[3]) - fmaxf(b1[1], b2[1]), 0.f);
    float inter = ix * iy;
    float iou = inter / (a1 + a2 - inter + 1e-6f);
    float f[18];
    f[0] = c1x / w;  f[1] = c1y / h;  f[2] = c2x / w;  f[3] = c2y / h;
    f[4] = w1 / w;   f[5] = h1 / h;   f[6] = w2 / w;   f[7] = h2 / h;
    f[8] = a1 / (h * w); f[9] = a2 / (h * w); f[10] = a2 / (a1 + 1e-6f);
    f[11] = w1 / (h1 + 1e-6f); f[12] = w2 / (h2 + 1e-6f); f[13] = iou;
    f[14] = (c2x > c1x) ? dx : 0.f;  f[15] = (c2x < c1x) ? dx : 0.f;
    f[16] = (c2y > c1y) ? dy : 0.f;  f[17] = (c2y < c1y) ? dy : 0.f;
    float* o = f36 + (int64_t)li * 36;
#pragma unroll
    for (int i = 0; i < 18; ++i) {
        o[i] = f[i];
        o[18 + i] = logf(f[i] + 1e-6f);
    }
}

// ---------------- encoder self-attention (T=S=128, dh=32), per (b,head) block ----------------
__global__ __launch_bounds__(128) void enc_attn_k(
    const float* __restrict__ q, const float* __restrict__ k,
    const float* __restrict__ v, float* __restrict__ out)
{
    int b = blockIdx.x >> 3, hd = blockIdx.x & 7;
    __shared__ float kl[128][32];
    __shared__ float vl[128][32];
    int tid = threadIdx.x;
    for (int i = tid; i < 128 * 32; i += 128) {
        int s = i >> 5, j = i & 31;
        int64_t off = ((int64_t)b * N + s) * 256 + hd * 32 + j;
        kl[s][j] = k[off];
        vl[s][j] = v[off];
    }
    __syncthreads();
    int t = tid;
    int64_t qoff = ((int64_t)b * N + t) * 256 + hd * 32;
    float qr[32];
#pragma unroll
    for (int j = 0; j < 32; ++j) qr[j] = q[qoff + j] * QSCALE;
    float m = -1e30f, l = 0.f;
    for (int s = 0; s < 128; ++s) {
        float d = 0.f;
#pragma unroll
        for (int j = 0; j < 32; ++j) d += qr[j] * kl[s][j];
        float mn = fmaxf(m, d);
        l = l * __expf(m - mn) + __expf(d - mn);
        m = mn;
    }
    float acc[32] = {};
    for (int s = 0; s < 128; ++s) {
        float d = 0.f;
#pragma unroll
        for (int j = 0; j < 32; ++j) d += qr[j] * kl[s][j];
        float wgt = __expf(d - m);
#pragma unroll
        for (int j = 0; j < 32; ++j) acc[j] += wgt * vl[s][j];
    }
    float linv = 1.f / l;
#pragma unroll
    for (int j = 0; j < 32; ++j) out[qoff + j] = acc[j] * linv;
}

// ---------------- decoder cross-attention (S=64, dh=32), chunk-local rows ----------------
// A 256-row block can straddle at most one batch boundary -> load K/V for both b's.
__global__ __launch_bounds__(256) void dec_attn_k(
    const float* __restrict__ q, const float* __restrict__ kp,
    const float* __restrict__ vp, float* __restrict__ out,
    int chunk0, int rows)
{
    int hd = blockIdx.y;
    int r0 = blockIdx.x * 256;
    __shared__ float kl[2][64][32];
    __shared__ float vl[2][64][32];
    int tid = threadIdx.x;
    int b0 = (chunk0 + r0) / P;
    int b1 = (chunk0 + r0 + 255) / P;
    if (b1 >= B) b1 = B - 1;
    for (int i = tid; i < 64 * 32; i += 256) {
        int s = i >> 5, j = i & 31;
        int64_t off0 = ((int64_t)b0 * MPOSE + s) * 256 + hd * 32 + j;
        int64_t off1 = ((int64_t)b1 * MPOSE + s) * 256 + hd * 32 + j;
        kl[0][s][j] = kp[off0];
        vl[0][s][j] = vp[off0];
        kl[1][s][j] = kp[off1];
        vl[1][s][j] = vp[off1];
    }
    __syncthreads();
    int r = r0 + tid;
    if (r >= rows) return;
    int which = ((chunk0 + r) / P == b0) ? 0 : 1;
    int64_t qoff = (int64_t)r * 256 + hd * 32;
    float qr[32];
#pragma unroll
    for (int j = 0; j < 32; ++j) qr[j] = q[qoff + j] * QSCALE;
    float m = -1e30f, l = 0.f;
    for (int s = 0; s < 64; ++s) {
        float d = 0.f;
#pragma unroll
        for (int j = 0; j < 32; ++j) d += qr[j] * kl[which][s][j];
        float mn = fmaxf(m, d);
        l = l * __expf(m - mn) + __expf(d - mn);
        m = mn;
    }
    float acc[32] = {};
    for (int s = 0; s < 64; ++s) {
        float d = 0.f;
#pragma unroll
        for (int j = 0; j < 32; ++j) d += qr[j] * kl[which][s][j];
        float wgt = __expf(d - m);
#pragma unroll
        for (int j = 0; j < 32; ++j) acc[j] += wgt * vl[which][s][j];
    }
    float linv = 1.f / l;
#pragma unroll
    for (int j = 0; j < 32; ++j) out[qoff + j] = acc[j] * linv;
}

// ---------------- pair gather for a chunk: h, o, pe_h, pe_o ----------------
__global__ __launch_bounds__(256) void gather_k(
    const float* __restrict__ x, const float* __restrict__ bpw,
    const float* __restrict__ lf,
    float* __restrict__ h, float* __restrict__ o,
    float* __restrict__ peh, float* __restrict__ peo, int chunk0)
{
    int li = blockIdx.x;
    int gp = chunk0 + li;
    int b = gp / P, p = gp - b * P;
    int c = threadIdx.x;
    int xi, yi; pair_xy(p, xi, yi);
    int64_t sx = ((int64_t)b * N + xi) * 256 + c;
    int64_t sy = ((int64_t)b * N + yi) * 256 + c;
    int64_t dst = (int64_t)li * 256 + c;
    float lfv = lf[b * 256 + c];
    h[dst]   = x[sx];
    o[dst]   = x[sy];
    peh[dst] = bpw[sx] + lfv;
    peo[dst] = bpw[sy] + lfv;
}

// ---------------- host orchestration ----------------
extern "C" void kernel_launch(void* const* d_in, const int* in_sizes, int n_in,
                              void* d_out, int out_size, void* d_ws, size_t ws_size,
                              hipStream_t stream)
{
    (void)in_sizes; (void)n_in; (void)out_size;
    const float* boxes     = (const float*)d_in[0];
    const float* embeds    = (const float*)d_in[1];
    const float* sizes     = (const float*)d_in[2];
    const float* pose      = (const float*)d_in[3];
    const float* line      = (const float*)d_in[4];
    const float* sw1 = (const float*)d_in[5];  const float* sb1 = (const float*)d_in[6];
    const float* sw2 = (const float*)d_in[7];  const float* sb2 = (const float*)d_in[8];
    const float* sw3 = (const float*)d_in[9];  const float* sb3 = (const float*)d_in[10];
    const float* bw  = (const float*)d_in[11]; const float* bb  = (const float*)d_in[12];
    const float* pw  = (const float*)d_in[13]; const float* pb  = (const float*)d_in[14];
    const float* lw  = (const float*)d_in[15]; const float* lb  = (const float*)d_in[16];
    const float* enc_pe_w  = (const float*)d_in[17]; const float* enc_pe_b = (const float*)d_in[18];
    const float* enc_qkv_w = (const float*)d_in[19]; const float* enc_qkv_b = (const float*)d_in[20];
    const float* enc_out_w = (const float*)d_in[21]; const float* enc_out_b = (const float*)d_in[22];
    const float* enc_ff1_w = (const float*)d_in[23]; const float* enc_ff1_b = (const float*)d_in[24];
    const float* enc_ff2_w = (const float*)d_in[25]; const float* enc_ff2_b = (const float*)d_in[26];
    const float* enc_ln1_g = (const float*)d_in[27]; const float* enc_ln1_b = (const float*)d_in[28];
    const float* enc_ln2_g = (const float*)d_in[29]; const float* enc_ln2_b = (const float*)d_in[30];
    const float* dec_q_w   = (const float*)d_in[31]; const float* dec_q_b  = (const float*)d_in[32];
    const float* dec_kv_w  = (const float*)d_in[33]; const float* dec_kv_b = (const float*)d_in[34];
    const float* dec_out_w = (const float*)d_in[35]; const float* dec_out_b = (const float*)d_in[36];
    const float* dec_ff1_w = (const float*)d_in[37]; const float* dec_ff1_b = (const float*)d_in[38];
    const float* dec_ff2_w = (const float*)d_in[39]; const float* dec_ff2_b = (const float*)d_in[40];
    const float* dec_ln1_g = (const float*)d_in[41]; const float* dec_ln1_b = (const float*)d_in[42];
    const float* dec_ln2_g = (const float*)d_in[43]; const float* dec_ln2_b = (const float*)d_in[44];
    const float* fc1_w = (const float*)d_in[45]; const float* fc1_b = (const float*)d_in[46];
    const float* fc2_w = (const float*)d_in[47]; const float* fc2_b = (const float*)d_in[48];
    const float* mln1_g = (const float*)d_in[49]; const float* mln1_b = (const float*)d_in[50];
    const float* mln2_g = (const float*)d_in[51]; const float* mln2_b = (const float*)d_in[52];
    const float* m1_w = (const float*)d_in[53]; const float* m1_b = (const float*)d_in[54];
    const float* m2_w = (const float*)d_in[55]; const float* m2_b = (const float*)d_in[56];
    float* out = (float*)d_out;

    // ---- workspace layout (floats), sized from the REAL ws_size ----
    float* base = (float*)d_ws;
    int64_t wsf = (int64_t)(ws_size / sizeof(float));
    // live across the whole call:
    float* x_   = base;                       // BN*256 = 524288
    float* bpw_ = x_   + 524288;              // 524288
    float* lf   = bpw_ + 524288;              // 4096
    float* kv0  = lf   + 4096;                // 4 x 262144 (kp0, vp0, kp1, vp1)
    float* arena = kv0 + 4 * 262144;
    const int64_t LIVE_F = arena - base;      // 2,101,248 floats (8.4 MB)
    int64_t arena_f = wsf - LIVE_F;
    if (arena_f < 0) arena_f = 0;

    // setup-phase views into arena (needed total: 6,062,080 floats = 24.3 MB)
    float* posx  = arena;                     // 524288
    float* boxpe = posx  + 524288;            // 1048576
    float* e_q   = boxpe + 1048576;           // 524288
    float* e_k   = e_q   + 524288;
    float* e_v   = e_k   + 524288;
    float* e_t   = e_v   + 524288;
    float* e_ff  = e_t   + 524288;            // 2097152
    float* pctx  = e_ff  + 2097152;           // 262144
    float* lm    = pctx  + 262144;            // 32768

    // chunk size: per-row need = 4*256 (h,o,peh,peo) + 256 (tB) + 1024 (tA) = 2304 floats
    int64_t rc = (arena_f / 2304) & ~63LL;
    if (rc > BP) rc = BP;
    if (rc < 64) rc = 64;

    // ---- stage A: small precomputes (arena = setup layout) ----
    line_mean_k<<<8192, 256, 0, stream>>>(line, lm);
    line_proj_k<<<16, 256, 0, stream>>>(lm, lw, lb, lf);
    boxpe_k<<<(int)BN, 512, 0, stream>>>(boxes, sizes, boxpe);
    gemm(stream, boxpe, nullptr, 512, enc_pe_w, 256, enc_pe_b, posx, 256, (int)BN, 256, 512, false, false, false);
    gemm(stream, boxpe, nullptr, 512, bw,       256, bb,       bpw_, 256, (int)BN, 256, 512, false, false, false);
    gemm(stream, pose,  nullptr, 768, pw,       256, pb,       pctx, 256, B*MPOSE, 256, 768, false, false, false);
    // decoder K/V for both layers (live region)
    for (int l = 0; l < 2; ++l) {
        const float* Wkv = dec_kv_w + (int64_t)l * 256 * 512;
        const float* bkv = dec_kv_b + (int64_t)l * 512;
        gemm(stream, pctx, nullptr, 256, Wkv,       512, bkv,       kv0 + (2*l+0)*262144, 256, B*MPOSE, 256, 256, false, false, false);
        gemm(stream, pctx, nullptr, 256, Wkv + 256, 512, bkv + 256, kv0 + (2*l+1)*262144, 256, B*MPOSE, 256, 256, false, false, false);
    }

    // ---- stage B: encoder (2 layers) on x_ ----
    hipMemcpyAsync(x_, embeds, BN * 256 * sizeof(float), hipMemcpyDeviceToDevice, stream);
    for (int i = 0; i < 2; ++i) {
        const float* Wqkv = enc_qkv_w + (int64_t)i * 256 * 768;
        const float* bqkv = enc_qkv_b + (int64_t)i * 768;
        gemm(stream, x_, posx, 256, Wqkv,       768, bqkv,       e_q, 256, (int)BN, 256, 256, false, false, false);
        gemm(stream, x_, posx, 256, Wqkv + 256, 768, bqkv + 256, e_k, 256, (int)BN, 256, 256, false, false, false);
        gemm(stream, x_, nullptr, 256, Wqkv + 512, 768, bqkv + 512, e_v, 256, (int)BN, 256, 256, false, false, false);
        enc_attn_k<<<B * 8, 128, 0, stream>>>(e_q, e_k, e_v, e_t);
        gemm(stream, e_t, nullptr, 256, enc_out_w + (int64_t)i * 65536, 256, enc_out_b + i * 256,
             e_q, 256, (int)BN, 256, 256, false, false, false);
        ln_k<<<(int)(BN / 4), 256, 0, stream>>>(x_, x_, e_q, enc_ln1_g + i * 256, enc_ln1_b + i * 256, (int)BN);
        gemm(stream, x_, nullptr, 256, enc_ff1_w + (int64_t)i * 262144, 1024, enc_ff1_b + i * 1024,
             e_ff, 1024, (int)BN, 1024, 256, true, false, false);
        gemm(stream, e_ff, nullptr, 1024, enc_ff2_w + (int64_t)i * 262144, 256, enc_ff2_b + i * 256,
             e_t, 256, (int)BN, 256, 1024, false, false, false);
        ln_k<<<(int)(BN / 4), 256, 0, stream>>>(x_, x_, e_t, enc_ln2_g + i * 256, enc_ln2_b + i * 256, (int)BN);
    }

    // ---- stage C: chunked pair pipeline (arena re-carved per chunk) ----
    for (int64_t c0 = 0; c0 < BP; c0 += rc) {
        int rows = (int)((BP - c0 < rc) ? (BP - c0) : rc);  // multiple of 64
        float* ch_h   = arena;
        float* ch_o   = ch_h   + (int64_t)rc * 256;
        float* ch_peh = ch_o   + (int64_t)rc * 256;
        float* ch_peo = ch_peh + (int64_t)rc * 256;
        float* ch_tB  = ch_peo + (int64_t)rc * 256;
        float* ch_tA  = ch_tB  + (int64_t)rc * 256;   // rc*1024 (z2 aliases here too)

        gather_k<<<rows, 256, 0, stream>>>(x_, bpw_, lf, ch_h, ch_o, ch_peh, ch_peo, (int)c0);

        // decoder: 2 layers x {h,o}
        for (int l = 0; l < 2; ++l) {
            const float* kp = kv0 + (2*l+0)*262144;
            const float* vp = kv0 + (2*l+1)*262144;
            for (int f = 0; f < 2; ++f) {
                float* feat = f ? ch_o  : ch_h;
                float* pe   = f ? ch_peo : ch_peh;
                gemm(stream, feat, pe, 256, dec_q_w + (int64_t)l * 65536, 256, dec_q_b + l * 256,
                     ch_tB, 256, rows, 256, 256, false, false, false);
                dec_attn_k<<<dim3((rows + 255) / 256, 8), 256, 0, stream>>>(ch_tB, kp, vp, ch_tA, (int)c0, rows);
                gemm(stream, ch_tA, nullptr, 256, dec_out_w + (int64_t)l * 65536, 256, dec_out_b + l * 256,
                     ch_tB, 256, rows, 256, 256, false, false, false);
                ln_k<<<rows / 4, 256, 0, stream>>>(feat, feat, ch_tB, dec_ln1_g + l * 256, dec_ln1_b + l * 256, rows);
                gemm(stream, feat, nullptr, 256, dec_ff1_w + (int64_t)l * 262144, 1024, dec_ff1_b + l * 1024,
                     ch_tA, 1024, rows, 1024, 256, true, false, false);
                gemm(stream, ch_tA, nullptr, 1024, dec_ff2_w + (int64_t)l * 262144, 256, dec_ff2_b + l * 256,
                     ch_tB, 256, rows, 256, 1024, false, false, false);
                ln_k<<<rows / 4, 256, 0, stream>>>(feat, feat, ch_tB, dec_ln2_g + l * 256, dec_ln2_b + l * 256, rows);
            }
        }

        // head (peh/peo now dead, reuse them)
        // hoLn -> ch_peh
        gemm(stream, ch_h, nullptr, 256, fc1_w,             256, fc1_b,   ch_peh, 256, rows, 256, 256, false, false, false);
        gemm(stream, ch_o, nullptr, 256, fc1_w + 256 * 256, 256, nullptr, ch_peh, 256, rows, 256, 256, false, true,  false);
        ln_k<<<rows / 4, 256, 0, stream>>>(ch_peh, ch_peh, nullptr, mln1_g, mln1_b, rows);
        // spatial MLP -> spLn in ch_tB
        f36_k<<<(rows + 255) / 256, 256, 0, stream>>>(boxes, sizes, ch_tB, (int)c0, rows);
        gemm(stream, ch_tB, nullptr, 36,  sw1, 128, sb1, ch_tA,  128, rows, 128, 36,  true, false, false);
        gemm(stream, ch_tA, nullptr, 128, sw2, 256, sb2, ch_tB,  256, rows, 256, 128, true, false, false);
        gemm(stream, ch_tB, nullptr, 256, sw3, 256, sb3, ch_peo, 256, rows, 256, 256, true, false, false);
        gemm(stream, ch_peo, nullptr, 256, fc2_w, 256, fc2_b, ch_tB, 256, rows, 256, 256, false, false, false);
        ln_k<<<rows / 4, 256, 0, stream>>>(ch_tB, ch_tB, nullptr, mln2_g, mln2_b, rows);
        // z2 = relu(relu([hoLn,spLn]) @ m1 + b)  -> ch_tA (rows x 384)
        gemm(stream, ch_peh, nullptr, 256, m1_w,             384, m1_b,    ch_tA, 384, rows, 384, 256, false, false, true);
        gemm(stream, ch_tB,  nullptr, 256, m1_w + 256 * 384, 384, nullptr, ch_tA, 384, rows, 384, 256, true,  true,  true);
        // out chunk
        gemm(stream, ch_tA, nullptr, 384, m2_w, 256, m2_b, out + c0 * 256, 256, rows, 256, 384, true, false, false);
    }
}

// Round 3
// 3615.424 us; speedup vs baseline: 3.8644x; 3.8644x over previous
//
#include <hip/hip_runtime.h>
#include <stdint.h>

// ---------------- problem dims (hard-coded from setup_inputs) ----------------
static constexpr int B      = 16;
static constexpr int N      = 128;
static constexpr int P      = 4064;     // 32*(128-1) kept pairs
static constexpr int MPOSE  = 64;
static constexpr int64_t BN = (int64_t)B * N;   // 2048
static constexpr int64_t BP = (int64_t)B * P;   // 65024 = 508*128

#define TWO_PI 6.283185307179586f
#define QSCALE 0.17677669529663687f  /* 1/sqrt(32) */

typedef __attribute__((ext_vector_type(4))) float f32x4;
typedef __attribute__((ext_vector_type(8))) short bf16x8;
typedef __attribute__((ext_vector_type(8))) unsigned short u16x8;

__device__ __forceinline__ unsigned short f2bf(float f) {
    union { float f; unsigned u; } v; v.f = f;
    unsigned r = (v.u + 0x7fffu + ((v.u >> 16) & 1u)) >> 16;   // RNE
    return (unsigned short)r;
}

__device__ __forceinline__ void pair_xy(int p, int& x, int& y) {
    x = p / 127;
    int r = p - x * 127;
    y = (r < x) ? r : r + 1;
}

// ---------------- weight prep: W[K][N] fp32 -> Wt[N][Kpad] bf16 (zero-pad K) ----------------
__global__ __launch_bounds__(256) void wprep_k(
    const float* __restrict__ W, int K, int Nn,
    unsigned short* __restrict__ Wt, int Kpad)
{
    __shared__ float s[32][33];
    int k0 = blockIdx.x * 32, n0 = blockIdx.y * 32;
    int tx = threadIdx.x & 31, ty = threadIdx.x >> 5;   // 32 x 8
#pragma unroll
    for (int i = 0; i < 4; ++i) {
        int k = k0 + ty + i * 8;
        s[ty + i * 8][tx] = (k < K) ? W[(int64_t)k * Nn + n0 + tx] : 0.f;
    }
    __syncthreads();
#pragma unroll
    for (int i = 0; i < 4; ++i) {
        int n = n0 + ty + i * 8;
        Wt[(int64_t)n * Kpad + k0 + tx] = f2bf(s[tx][ty + i * 8]);
    }
}

static void wprep(hipStream_t st, const float* W, int K, int Nn, unsigned short* Wt, int Kpad)
{
    dim3 g(Kpad / 32, Nn / 32);
    wprep_k<<<g, 256, 0, st>>>(W, K, Nn, Wt, Kpad);
}

// ---------------- bf16 MFMA GEMM: C = act( (A(+A2)) @ Wt^T + bias ) ----------------
// Tile 128x128, BK=32, 256 thr = 4 waves (2x2), per-wave 64x64 = 4x4 frags of 16x16x32.
// A fp32 row-major (lda), converted to bf16 during LDS staging. Bt bf16 [Ncols][ldk].
// Requires M%128==0, Ncols%128==0.
template <bool RELU_OUT, bool ADD_C, bool RELU_A>
__global__ __launch_bounds__(256) void bgemm_k(
    const float* __restrict__ A, const float* __restrict__ A2, int lda,
    const unsigned short* __restrict__ Bt, int ldk,
    const float* __restrict__ bias,
    float* __restrict__ C, int ldc,
    int K, int kSteps)
{
    __shared__ unsigned short As[128][40];   // 80B row stride (16B aligned, spread banks)
    __shared__ unsigned short Bs[128][40];
    const int tid  = threadIdx.x;
    const int lane = tid & 63;
    const int wave = tid >> 6;
    const int wr = wave >> 1, wc = wave & 1;
    const int row0 = blockIdx.y * 128, col0 = blockIdx.x * 128;
    const int l15 = lane & 15, l4 = lane >> 4;
    const int sr = tid >> 1;             // staging row/col 0..127
    const int sh = (tid & 1) * 16;       // k-half 0 / 16

    f32x4 acc[4][4] = {};

    for (int ks = 0; ks < kSteps; ++ks) {
        const int k0 = ks * 32;
        // ---- stage A: global fp32 (+A2, reluA) -> bf16 LDS ----
        {
            const int64_t off = (int64_t)(row0 + sr) * lda + k0 + sh;
            const float* ap = A + off;
            float v[16];
            if (k0 + sh + 16 <= K) {
#pragma unroll
                for (int i = 0; i < 4; ++i) {
                    float4 t = ((const float4*)ap)[i];
                    v[i*4+0] = t.x; v[i*4+1] = t.y; v[i*4+2] = t.z; v[i*4+3] = t.w;
                }
                if (A2) {
                    const float* ap2 = A2 + off;
#pragma unroll
                    for (int i = 0; i < 4; ++i) {
                        float4 t = ((const float4*)ap2)[i];
                        v[i*4+0] += t.x; v[i*4+1] += t.y; v[i*4+2] += t.z; v[i*4+3] += t.w;
                    }
                }
            } else {
#pragma unroll
                for (int j = 0; j < 16; ++j) {
                    int gk = k0 + sh + j;
                    float x = 0.f;
                    if (gk < K) {
                        x = ap[j];
                        if (A2) x += A2[off + j];
                    }
                    v[j] = x;
                }
            }
            if (RELU_A) {
#pragma unroll
                for (int j = 0; j < 16; ++j) v[j] = fmaxf(v[j], 0.f);
            }
            u16x8 p0, p1;
#pragma unroll
            for (int j = 0; j < 8; ++j) { p0[j] = f2bf(v[j]); p1[j] = f2bf(v[8 + j]); }
            *(u16x8*)&As[sr][sh]     = p0;
            *(u16x8*)&As[sr][sh + 8] = p1;
        }
        // ---- stage B: bf16 global -> LDS ----
        {
            const unsigned short* bp = Bt + (int64_t)(col0 + sr) * ldk + k0 + sh;
            u16x8 q0 = *(const u16x8*)bp;
            u16x8 q1 = *(const u16x8*)(bp + 8);
            *(u16x8*)&Bs[sr][sh]     = q0;
            *(u16x8*)&Bs[sr][sh + 8] = q1;
        }
        __syncthreads();
        bf16x8 af[4], bfr[4];
#pragma unroll
        for (int f = 0; f < 4; ++f) {
            af[f]  = *(const bf16x8*)&As[wr * 64 + f * 16 + l15][l4 * 8];
            bfr[f] = *(const bf16x8*)&Bs[wc * 64 + f * 16 + l15][l4 * 8];
        }
#pragma unroll
        for (int i = 0; i < 4; ++i)
#pragma unroll
            for (int j = 0; j < 4; ++j)
                acc[i][j] = __builtin_amdgcn_mfma_f32_16x16x32_bf16(af[i], bfr[j], acc[i][j], 0, 0, 0);
        __syncthreads();
    }
    // ---- epilogue: bias / addC / relu, fp32 store ----
#pragma unroll
    for (int i = 0; i < 4; ++i) {
        int rb = row0 + wr * 64 + i * 16 + l4 * 4;
#pragma unroll
        for (int j = 0; j < 4; ++j) {
            int c = col0 + wc * 64 + j * 16 + l15;
            float bv = bias ? bias[c] : 0.f;
#pragma unroll
            for (int e = 0; e < 4; ++e) {
                int64_t off = (int64_t)(rb + e) * ldc + c;
                float vv = acc[i][j][e] + bv;
                if (ADD_C) vv += C[off];
                if (RELU_OUT) vv = fmaxf(vv, 0.f);
                C[off] = vv;
            }
        }
    }
}

static void bgemm(hipStream_t st,
                  const float* A, const float* A2, int lda,
                  const unsigned short* Bt, int ldk, const float* bias,
                  float* C, int ldc, int M, int Ncols, int K,
                  bool reluOut, bool addC, bool reluA)
{
    int kSteps = (K + 31) / 32;
    dim3 g(Ncols / 128, M / 128), b(256);
    if (!reluOut && !addC && !reluA)
        bgemm_k<false,false,false><<<g,b,0,st>>>(A,A2,lda,Bt,ldk,bias,C,ldc,K,kSteps);
    else if (reluOut && !addC && !reluA)
        bgemm_k<true,false,false><<<g,b,0,st>>>(A,A2,lda,Bt,ldk,bias,C,ldc,K,kSteps);
    else if (!reluOut && addC && !reluA)
        bgemm_k<false,true,false><<<g,b,0,st>>>(A,A2,lda,Bt,ldk,bias,C,ldc,K,kSteps);
    else if (!reluOut && !addC && reluA)
        bgemm_k<false,false,true><<<g,b,0,st>>>(A,A2,lda,Bt,ldk,bias,C,ldc,K,kSteps);
    else if (reluOut && addC && reluA)
        bgemm_k<true,true,true><<<g,b,0,st>>>(A,A2,lda,Bt,ldk,bias,C,ldc,K,kSteps);
    else
        bgemm_k<true,true,false><<<g,b,0,st>>>(A,A2,lda,Bt,ldk,bias,C,ldc,K,kSteps);
}

// ---------------- LayerNorm (D=256), optional residual, in-place safe ----------------
__global__ __launch_bounds__(256) void ln_k(
    float* __restrict__ out, const float* __restrict__ x, const float* __restrict__ res,
    const float* __restrict__ g, const float* __restrict__ be, int rows)
{
    int wave = threadIdx.x >> 6, lane = threadIdx.x & 63;
    int row = blockIdx.x * 4 + wave;
    if (row >= rows) return;
    int64_t base = (int64_t)row * 256 + lane * 4;
    float4 v = *(const float4*)(x + base);
    if (res) {
        float4 r = *(const float4*)(res + base);
        v.x += r.x; v.y += r.y; v.z += r.z; v.w += r.w;
    }
    float s  = v.x + v.y + v.z + v.w;
    float sq = v.x*v.x + v.y*v.y + v.z*v.z + v.w*v.w;
#pragma unroll
    for (int off = 1; off < 64; off <<= 1) {
        s  += __shfl_xor(s, off);
        sq += __shfl_xor(sq, off);
    }
    float m = s * (1.f/256.f);
    float var = sq * (1.f/256.f) - m * m;
    float inv = rsqrtf(var + 1e-5f);
    int c = lane * 4;
    float4 gg = *(const float4*)(g + c);
    float4 bb = *(const float4*)(be + c);
    float4 o;
    o.x = (v.x - m) * inv * gg.x + bb.x;
    o.y = (v.y - m) * inv * gg.y + bb.y;
    o.z = (v.z - m) * inv * gg.z + bb.z;
    o.w = (v.w - m) * inv * gg.w + bb.w;
    *(float4*)(out + base) = o;
}

// ---------------- line: mean over 8x8, then small proj (16x2048x256) ----------------
__global__ __launch_bounds__(256) void line_mean_k(const float* __restrict__ line, float* __restrict__ lm)
{
    int wave = threadIdx.x >> 6, lane = threadIdx.x & 63;
    int bc = blockIdx.x * 4 + wave;
    float v = line[(int64_t)bc * 64 + lane];
#pragma unroll
    for (int off = 1; off < 64; off <<= 1) v += __shfl_xor(v, off);
    if (lane == 0) lm[bc] = v * (1.f/64.f);
}

__global__ __launch_bounds__(256) void line_proj_k(
    const float* __restrict__ lm, const float* __restrict__ lw,
    const float* __restrict__ lb, float* __restrict__ lf)
{
    int b = blockIdx.x, j = threadIdx.x;
    float acc = lb[j];
    const float* lmb = lm + (int64_t)b * 2048;
    for (int c = 0; c < 2048; ++c) acc += lmb[c] * lw[(int64_t)c * 256 + j];
    lf[b * 256 + j] = acc;
}

// ---------------- sinusoidal box PE: (B,N,512) = [pe(cy),pe(cx),pe(h),pe(w)] ----------------
__global__ __launch_bounds__(512) void boxpe_k(
    const float* __restrict__ boxes, const float* __restrict__ sizes, float* __restrict__ boxpe)
{
    int row = blockIdx.x;
    int b = row >> 7;
    int i = threadIdx.x;
    const float* bx = boxes + (int64_t)row * 4;
    float h = sizes[b * 2 + 0], w = sizes[b * 2 + 1];
    float x0 = bx[0] / w, y0 = bx[1] / h, x1 = bx[2] / w, y1 = bx[3] / h;
    int seg = i >> 7, j = i & 127, k = j >> 1;
    float val;
    switch (seg) {
        case 0: val = (y0 + y1) * 0.5f; break;
        case 1: val = (x0 + x1) * 0.5f; break;
        case 2: val = (y1 - y0); break;
        default: val = (x1 - x0); break;
    }
    float dimt = powf(20.f, (float)k * (1.f/64.f));
    float arg = val * TWO_PI / dimt;
    boxpe[(int64_t)row * 512 + i] = (j & 1) ? cosf(arg) : sinf(arg);
}

// ---------------- spatial 36 features for a chunk of kept pairs ----------------
__global__ __launch_bounds__(256) void f36_k(
    const float* __restrict__ boxes, const float* __restrict__ sizes,
    float* __restrict__ f36, int chunk0, int cnt)
{
    int li = blockIdx.x * 256 + threadIdx.x;
    if (li >= cnt) return;
    int gp = chunk0 + li;
    int b = gp / P, p = gp - b * P;
    int xi, yi; pair_xy(p, xi, yi);
    const float* b1 = boxes + ((int64_t)b * N + xi) * 4;
    const float* b2 = boxes + ((int64_t)b * N + yi) * 4;
    float h = sizes[b * 2 + 0], w = sizes[b * 2 + 1];
    float c1x = (b1[0] + b1[2]) * 0.5f, c1y = (b1[1] + b1[3]) * 0.5f;
    float c2x = (b2[0] + b2[2]) * 0.5f, c2y = (b2[1] + b2[3]) * 0.5f;
    float w1 = b1[2] - b1[0], h1 = b1[3] - b1[1];
    float w2 = b2[2] - b2[0], h2 = b2[3] - b2[1];
    float a1 = w1 * h1, a2 = w2 * h2;
    float dx = fabsf(c2x - c1x) / (w1 + 1e-6f);
    float dy = fabsf(c2y - c1y) / (h1 + 1e-6f);
    float ix = fmaxf(fminf(b1[2], b2[2]) - fmaxf(b1[0], b2[0]), 0.f);
    float iy = fmaxf(fminf(b1[3], b2[3]) - fmaxf(b1[1], b2[1]), 0.f);
    float inter = ix * iy;
    float iou = inter / (a1 + a2 - inter + 1e-6f);
    float f[18];
    f[0] = c1x / w;  f[1] = c1y / h;  f[2] = c2x / w;  f[3] = c2y / h;
    f[4] = w1 / w;   f[5] = h1 / h;   f[6] = w2 / w;   f[7] = h2 / h;
    f[8] = a1 / (h * w); f[9] = a2 / (h * w); f[10] = a2 / (a1 + 1e-6f);
    f[11] = w1 / (h1 + 1e-6f); f[12] = w2 / (h2 + 1e-6f); f[13] = iou;
    f[14] = (c2x > c1x) ? dx : 0.f;  f[15] = (c2x < c1x) ? dx : 0.f;
    f[16] = (c2y > c1y) ? dy : 0.f;  f[17] = (c2y < c1y) ? dy : 0.f;
    float* o = f36 + (int64_t)li * 36;
#pragma unroll
    for (int i = 0; i < 18; ++i) {
        o[i] = f[i];
        o[18 + i] = logf(f[i] + 1e-6f);
    }
}

// ---------------- encoder self-attention (T=S=128, dh=32), per (b,head) block ----------------
__global__ __launch_bounds__(128) void enc_attn_k(
    const float* __restrict__ q, const float* __restrict__ k,
    const float* __restrict__ v, float* __restrict__ out)
{
    int b = blockIdx.x >> 3, hd = blockIdx.x & 7;
    __shared__ float kl[128][32];
    __shared__ float vl[128][32];
    int tid = threadIdx.x;
    for (int i = tid; i < 128 * 32; i += 128) {
        int s = i >> 5, j = i & 31;
        int64_t off = ((int64_t)b * N + s) * 256 + hd * 32 + j;
        kl[s][j] = k[off];
        vl[s][j] = v[off];
    }
    __syncthreads();
    int t = tid;
    int64_t qoff = ((int64_t)b * N + t) * 256 + hd * 32;
    float qr[32];
#pragma unroll
    for (int j = 0; j < 32; ++j) qr[j] = q[qoff + j] * QSCALE;
    float m = -1e30f, l = 0.f;
    for (int s = 0; s < 128; ++s) {
        float d = 0.f;
#pragma unroll
        for (int j = 0; j < 32; ++j) d += qr[j] * kl[s][j];
        float mn = fmaxf(m, d);
        l = l * __expf(m - mn) + __expf(d - mn);
        m = mn;
    }
    float acc[32] = {};
    for (int s = 0; s < 128; ++s) {
        float d = 0.f;
#pragma unroll
        for (int j = 0; j < 32; ++j) d += qr[j] * kl[s][j];
        float wgt = __expf(d - m);
#pragma unroll
        for (int j = 0; j < 32; ++j) acc[j] += wgt * vl[s][j];
    }
    float linv = 1.f / l;
#pragma unroll
    for (int j = 0; j < 32; ++j) out[qoff + j] = acc[j] * linv;
}

// ---------------- decoder cross-attention (S=64, dh=32), chunk-local rows ----------------
__global__ __launch_bounds__(256) void dec_attn_k(
    const float* __restrict__ q, const float* __restrict__ kp,
    const float* __restrict__ vp, float* __restrict__ out,
    int chunk0, int rows)
{
    int hd = blockIdx.y;
    int r0 = blockIdx.x * 256;
    __shared__ float kl[2][64][32];
    __shared__ float vl[2][64][32];
    int tid = threadIdx.x;
    int b0 = (chunk0 + r0) / P;
    int b1 = (chunk0 + r0 + 255) / P;
    if (b1 >= B) b1 = B - 1;
    for (int i = tid; i < 64 * 32; i += 256) {
        int s = i >> 5, j = i & 31;
        int64_t off0 = ((int64_t)b0 * MPOSE + s) * 256 + hd * 32 + j;
        int64_t off1 = ((int64_t)b1 * MPOSE + s) * 256 + hd * 32 + j;
        kl[0][s][j] = kp[off0];
        vl[0][s][j] = vp[off0];
        kl[1][s][j] = kp[off1];
        vl[1][s][j] = vp[off1];
    }
    __syncthreads();
    int r = r0 + tid;
    if (r >= rows) return;
    int which = ((chunk0 + r) / P == b0) ? 0 : 1;
    int64_t qoff = (int64_t)r * 256 + hd * 32;
    float qr[32];
#pragma unroll
    for (int j = 0; j < 32; ++j) qr[j] = q[qoff + j] * QSCALE;
    float m = -1e30f, l = 0.f;
    for (int s = 0; s < 64; ++s) {
        float d = 0.f;
#pragma unroll
        for (int j = 0; j < 32; ++j) d += qr[j] * kl[which][s][j];
        float mn = fmaxf(m, d);
        l = l * __expf(m - mn) + __expf(d - mn);
        m = mn;
    }
    float acc[32] = {};
    for (int s = 0; s < 64; ++s) {
        float d = 0.f;
#pragma unroll
        for (int j = 0; j < 32; ++j) d += qr[j] * kl[which][s][j];
        float wgt = __expf(d - m);
#pragma unroll
        for (int j = 0; j < 32; ++j) acc[j] += wgt * vl[which][s][j];
    }
    float linv = 1.f / l;
#pragma unroll
    for (int j = 0; j < 32; ++j) out[qoff + j] = acc[j] * linv;
}

// ---------------- pair gather for a chunk: h, o, pe_h, pe_o ----------------
__global__ __launch_bounds__(256) void gather_k(
    const float* __restrict__ x, const float* __restrict__ bpw,
    const float* __restrict__ lf,
    float* __restrict__ h, float* __restrict__ o,
    float* __restrict__ peh, float* __restrict__ peo, int chunk0)
{
    int li = blockIdx.x;
    int gp = chunk0 + li;
    int b = gp / P, p = gp - b * P;
    int c = threadIdx.x;
    int xi, yi; pair_xy(p, xi, yi);
    int64_t sx = ((int64_t)b * N + xi) * 256 + c;
    int64_t sy = ((int64_t)b * N + yi) * 256 + c;
    int64_t dst = (int64_t)li * 256 + c;
    float lfv = lf[b * 256 + c];
    h[dst]   = x[sx];
    o[dst]   = x[sy];
    peh[dst] = bpw[sx] + lfv;
    peo[dst] = bpw[sy] + lfv;
}

// ---------------- bf16 weight arena offsets (ushort units) ----------------
static constexpr int64_t WT_QKV  = 0;                      // 2 x 768x256
static constexpr int64_t WT_EOUT = WT_QKV  + 2*196608;     // 2 x 256x256
static constexpr int64_t WT_EFF1 = WT_EOUT + 2*65536;      // 2 x 1024x256
static constexpr int64_t WT_EFF2 = WT_EFF1 + 2*262144;     // 2 x 256x1024
static constexpr int64_t WT_DQ   = WT_EFF2 + 2*262144;     // 2 x 256x256
static constexpr int64_t WT_DKV  = WT_DQ   + 2*65536;      // 2 x 512x256
static constexpr int64_t WT_DOUT = WT_DKV  + 2*131072;     // 2 x 256x256
static constexpr int64_t WT_DFF1 = WT_DOUT + 2*65536;      // 2 x 1024x256
static constexpr int64_t WT_DFF2 = WT_DFF1 + 2*262144;     // 2 x 256x1024
static constexpr int64_t WT_SW1  = WT_DFF2 + 2*262144;     // 128x64
static constexpr int64_t WT_SW2  = WT_SW1 + 8192;          // 256x128
static constexpr int64_t WT_SW3  = WT_SW2 + 32768;         // 256x256
static constexpr int64_t WT_BW   = WT_SW3 + 65536;         // 256x512
static constexpr int64_t WT_PW   = WT_BW  + 131072;        // 256x768
static constexpr int64_t WT_EPE  = WT_PW  + 196608;        // 256x512
static constexpr int64_t WT_FC1  = WT_EPE + 131072;        // 256x512
static constexpr int64_t WT_FC2  = WT_FC1 + 131072;        // 256x256
static constexpr int64_t WT_M1   = WT_FC2 + 65536;         // 384x512
static constexpr int64_t WT_M2   = WT_M1  + 196608;        // 256x384
static constexpr int64_t WT_TOTAL = WT_M2 + 98304;         // 4,202,496 ushorts

// ---------------- host orchestration ----------------
extern "C" void kernel_launch(void* const* d_in, const int* in_sizes, int n_in,
                              void* d_out, int out_size, void* d_ws, size_t ws_size,
                              hipStream_t stream)
{
    (void)in_sizes; (void)n_in; (void)out_size;
    const float* boxes     = (const float*)d_in[0];
    const float* embeds    = (const float*)d_in[1];
    const float* sizes     = (const float*)d_in[2];
    const float* pose      = (const float*)d_in[3];
    const float* line      = (const float*)d_in[4];
    const float* sw1 = (const float*)d_in[5];  const float* sb1 = (const float*)d_in[6];
    const float* sw2 = (const float*)d_in[7];  const float* sb2 = (const float*)d_in[8];
    const float* sw3 = (const float*)d_in[9];  const float* sb3 = (const float*)d_in[10];
    const float* bw  = (const float*)d_in[11]; const float* bb  = (const float*)d_in[12];
    const float* pw  = (const float*)d_in[13]; const float* pb  = (const float*)d_in[14];
    const float* lw  = (const float*)d_in[15]; const float* lb  = (const float*)d_in[16];
    const float* enc_pe_w  = (const float*)d_in[17]; const float* enc_pe_b = (const float*)d_in[18];
    const float* enc_qkv_w = (const float*)d_in[19]; const float* enc_qkv_b = (const float*)d_in[20];
    const float* enc_out_w = (const float*)d_in[21]; const float* enc_out_b = (const float*)d_in[22];
    const float* enc_ff1_w = (const float*)d_in[23]; const float* enc_ff1_b = (const float*)d_in[24];
    const float* enc_ff2_w = (const float*)d_in[25]; const float* enc_ff2_b = (const float*)d_in[26];
    const float* enc_ln1_g = (const float*)d_in[27]; const float* enc_ln1_b = (const float*)d_in[28];
    const float* enc_ln2_g = (const float*)d_in[29]; const float* enc_ln2_b = (const float*)d_in[30];
    const float* dec_q_w   = (const float*)d_in[31]; const float* dec_q_b  = (const float*)d_in[32];
    const float* dec_kv_w  = (const float*)d_in[33]; const float* dec_kv_b = (const float*)d_in[34];
    const float* dec_out_w = (const float*)d_in[35]; const float* dec_out_b = (const float*)d_in[36];
    const float* dec_ff1_w = (const float*)d_in[37]; const float* dec_ff1_b = (const float*)d_in[38];
    const float* dec_ff2_w = (const float*)d_in[39]; const float* dec_ff2_b = (const float*)d_in[40];
    const float* dec_ln1_g = (const float*)d_in[41]; const float* dec_ln1_b = (const float*)d_in[42];
    const float* dec_ln2_g = (const float*)d_in[43]; const float* dec_ln2_b = (const float*)d_in[44];
    const float* fc1_w = (const float*)d_in[45]; const float* fc1_b = (const float*)d_in[46];
    const float* fc2_w = (const float*)d_in[47]; const float* fc2_b = (const float*)d_in[48];
    const float* mln1_g = (const float*)d_in[49]; const float* mln1_b = (const float*)d_in[50];
    const float* mln2_g = (const float*)d_in[51]; const float* mln2_b = (const float*)d_in[52];
    const float* m1_w = (const float*)d_in[53]; const float* m1_b = (const float*)d_in[54];
    const float* m2_w = (const float*)d_in[55]; const float* m2_b = (const float*)d_in[56];
    float* out = (float*)d_out;

    // ---- workspace layout (floats), sized from the REAL ws_size ----
    float* base = (float*)d_ws;
    int64_t wsf = (int64_t)(ws_size / sizeof(float));
    float* x_   = base;                       // 524288
    float* bpw_ = x_   + 524288;              // 524288
    float* lf   = bpw_ + 524288;              // 4096
    float* kv0  = lf   + 4096;                // 4 x 262144
    unsigned short* wt = (unsigned short*)(kv0 + 4 * 262144);   // WT_TOTAL ushorts
    float* arena = (float*)(wt + WT_TOTAL);
    const int64_t LIVE_F = arena - base;
    int64_t arena_f = wsf - LIVE_F;
    if (arena_f < 0) arena_f = 0;

    // setup-phase views into arena
    float* posx  = arena;                     // 524288
    float* boxpe = posx  + 524288;            // 1048576
    float* e_q   = boxpe + 1048576;
    float* e_k   = e_q   + 524288;
    float* e_v   = e_k   + 524288;
    float* e_t   = e_v   + 524288;
    float* e_ff  = e_t   + 524288;            // 2097152
    float* pctx  = e_ff  + 2097152;           // 262144
    float* lm    = pctx  + 262144;            // 32768

    // chunk rows: per-row = 4*256 + 256 + 1024 = 2304 floats; multiple of 128
    int64_t rc = (arena_f / 2304) & ~127LL;
    if (rc > BP) rc = BP;
    if (rc < 128) rc = 128;

    // ---- stage 0: weight prep (transpose + bf16) ----
    for (int i = 0; i < 2; ++i) {
        wprep(stream, enc_qkv_w + (int64_t)i*196608, 256, 768,  wt + WT_QKV  + i*196608, 256);
        wprep(stream, enc_out_w + (int64_t)i*65536,  256, 256,  wt + WT_EOUT + i*65536,  256);
        wprep(stream, enc_ff1_w + (int64_t)i*262144, 256, 1024, wt + WT_EFF1 + i*262144, 256);
        wprep(stream, enc_ff2_w + (int64_t)i*262144, 1024, 256, wt + WT_EFF2 + i*262144, 1024);
        wprep(stream, dec_q_w   + (int64_t)i*65536,  256, 256,  wt + WT_DQ   + i*65536,  256);
        wprep(stream, dec_kv_w  + (int64_t)i*131072, 256, 512,  wt + WT_DKV  + i*131072, 256);
        wprep(stream, dec_out_w + (int64_t)i*65536,  256, 256,  wt + WT_DOUT + i*65536,  256);
        wprep(stream, dec_ff1_w + (int64_t)i*262144, 256, 1024, wt + WT_DFF1 + i*262144, 256);
        wprep(stream, dec_ff2_w + (int64_t)i*262144, 1024, 256, wt + WT_DFF2 + i*262144, 1024);
    }
    wprep(stream, sw1, 36, 128,  wt + WT_SW1, 64);
    wprep(stream, sw2, 128, 256, wt + WT_SW2, 128);
    wprep(stream, sw3, 256, 256, wt + WT_SW3, 256);
    wprep(stream, bw,  512, 256, wt + WT_BW,  512);
    wprep(stream, pw,  768, 256, wt + WT_PW,  768);
    wprep(stream, enc_pe_w, 512, 256, wt + WT_EPE, 512);
    wprep(stream, fc1_w, 512, 256, wt + WT_FC1, 512);
    wprep(stream, fc2_w, 256, 256, wt + WT_FC2, 256);
    wprep(stream, m1_w, 512, 384, wt + WT_M1, 512);
    wprep(stream, m2_w, 384, 256, wt + WT_M2, 384);

    // ---- stage A: small precomputes ----
    line_mean_k<<<8192, 256, 0, stream>>>(line, lm);
    line_proj_k<<<16, 256, 0, stream>>>(lm, lw, lb, lf);
    boxpe_k<<<(int)BN, 512, 0, stream>>>(boxes, sizes, boxpe);
    bgemm(stream, boxpe, nullptr, 512, wt + WT_EPE, 512, enc_pe_b, posx, 256, (int)BN, 256, 512, false, false, false);
    bgemm(stream, boxpe, nullptr, 512, wt + WT_BW,  512, bb,       bpw_, 256, (int)BN, 256, 512, false, false, false);
    bgemm(stream, pose,  nullptr, 768, wt + WT_PW,  768, pb,       pctx, 256, B*MPOSE, 256, 768, false, false, false);
    // decoder K/V for both layers
    for (int l = 0; l < 2; ++l) {
        const float* bkv = dec_kv_b + (int64_t)l * 512;
        bgemm(stream, pctx, nullptr, 256, wt + WT_DKV + l*131072,         256, bkv,       kv0 + (2*l+0)*262144, 256, B*MPOSE, 256, 256, false, false, false);
        bgemm(stream, pctx, nullptr, 256, wt + WT_DKV + l*131072 + 65536, 256, bkv + 256, kv0 + (2*l+1)*262144, 256, B*MPOSE, 256, 256, false, false, false);
    }

    // ---- stage B: encoder (2 layers) on x_ ----
    hipMemcpyAsync(x_, embeds, BN * 256 * sizeof(float), hipMemcpyDeviceToDevice, stream);
    for (int i = 0; i < 2; ++i) {
        const unsigned short* Wq = wt + WT_QKV + (int64_t)i * 196608;
        const float* bqkv = enc_qkv_b + (int64_t)i * 768;
        bgemm(stream, x_, posx, 256, Wq,          256, bqkv,       e_q, 256, (int)BN, 256, 256, false, false, false);
        bgemm(stream, x_, posx, 256, Wq + 65536,  256, bqkv + 256, e_k, 256, (int)BN, 256, 256, false, false, false);
        bgemm(stream, x_, nullptr, 256, Wq + 131072, 256, bqkv + 512, e_v, 256, (int)BN, 256, 256, false, false, false);
        enc_attn_k<<<B * 8, 128, 0, stream>>>(e_q, e_k, e_v, e_t);
        bgemm(stream, e_t, nullptr, 256, wt + WT_EOUT + (int64_t)i*65536, 256, enc_out_b + i * 256,
              e_q, 256, (int)BN, 256, 256, false, false, false);
        ln_k<<<(int)(BN / 4), 256, 0, stream>>>(x_, x_, e_q, enc_ln1_g + i * 256, enc_ln1_b + i * 256, (int)BN);
        bgemm(stream, x_, nullptr, 256, wt + WT_EFF1 + (int64_t)i*262144, 256, enc_ff1_b + i * 1024,
              e_ff, 1024, (int)BN, 1024, 256, true, false, false);
        bgemm(stream, e_ff, nullptr, 1024, wt + WT_EFF2 + (int64_t)i*262144, 1024, enc_ff2_b + i * 256,
              e_t, 256, (int)BN, 256, 1024, false, false, false);
        ln_k<<<(int)(BN / 4), 256, 0, stream>>>(x_, x_, e_t, enc_ln2_g + i * 256, enc_ln2_b + i * 256, (int)BN);
    }

    // ---- stage C: chunked pair pipeline ----
    for (int64_t c0 = 0; c0 < BP; c0 += rc) {
        int rows = (int)((BP - c0 < rc) ? (BP - c0) : rc);   // multiple of 128
        float* ch_h   = arena;
        float* ch_o   = ch_h   + (int64_t)rc * 256;
        float* ch_peh = ch_o   + (int64_t)rc * 256;
        float* ch_peo = ch_peh + (int64_t)rc * 256;
        float* ch_tB  = ch_peo + (int64_t)rc * 256;
        float* ch_tA  = ch_tB  + (int64_t)rc * 256;   // rc*1024

        gather_k<<<rows, 256, 0, stream>>>(x_, bpw_, lf, ch_h, ch_o, ch_peh, ch_peo, (int)c0);

        for (int l = 0; l < 2; ++l) {
            const float* kp = kv0 + (2*l+0)*262144;
            const float* vp = kv0 + (2*l+1)*262144;
            for (int f = 0; f < 2; ++f) {
                float* feat = f ? ch_o  : ch_h;
                float* pe   = f ? ch_peo : ch_peh;
                bgemm(stream, feat, pe, 256, wt + WT_DQ + (int64_t)l*65536, 256, dec_q_b + l * 256,
                      ch_tB, 256, rows, 256, 256, false, false, false);
                dec_attn_k<<<dim3((rows + 255) / 256, 8), 256, 0, stream>>>(ch_tB, kp, vp, ch_tA, (int)c0, rows);
                bgemm(stream, ch_tA, nullptr, 256, wt + WT_DOUT + (int64_t)l*65536, 256, dec_out_b + l * 256,
                      ch_tB, 256, rows, 256, 256, false, false, false);
                ln_k<<<rows / 4, 256, 0, stream>>>(feat, feat, ch_tB, dec_ln1_g + l * 256, dec_ln1_b + l * 256, rows);
                bgemm(stream, feat, nullptr, 256, wt + WT_DFF1 + (int64_t)l*262144, 256, dec_ff1_b + l * 1024,
                      ch_tA, 1024, rows, 1024, 256, true, false, false);
                bgemm(stream, ch_tA, nullptr, 1024, wt + WT_DFF2 + (int64_t)l*262144, 1024, dec_ff2_b + l * 256,
                      ch_tB, 256, rows, 256, 1024, false, false, false);
                ln_k<<<rows / 4, 256, 0, stream>>>(feat, feat, ch_tB, dec_ln2_g + l * 256, dec_ln2_b + l * 256, rows);
            }
        }

        // head (peh/peo now dead, reuse)
        bgemm(stream, ch_h, nullptr, 256, wt + WT_FC1,       512, fc1_b,   ch_peh, 256, rows, 256, 256, false, false, false);
        bgemm(stream, ch_o, nullptr, 256, wt + WT_FC1 + 256, 512, nullptr, ch_peh, 256, rows, 256, 256, false, true,  false);
        ln_k<<<rows / 4, 256, 0, stream>>>(ch_peh, ch_peh, nullptr, mln1_g, mln1_b, rows);
        f36_k<<<(rows + 255) / 256, 256, 0, stream>>>(boxes, sizes, ch_tB, (int)c0, rows);
        bgemm(stream, ch_tB, nullptr, 36,  wt + WT_SW1, 64,  sb1, ch_tA,  128, rows, 128, 36,  true, false, false);
        bgemm(stream, ch_tA, nullptr, 128, wt + WT_SW2, 128, sb2, ch_tB,  256, rows, 256, 128, true, false, false);
        bgemm(stream, ch_tB, nullptr, 256, wt + WT_SW3, 256, sb3, ch_peo, 256, rows, 256, 256, true, false, false);
        bgemm(stream, ch_peo, nullptr, 256, wt + WT_FC2, 256, fc2_b, ch_tB, 256, rows, 256, 256, false, false, false);
        ln_k<<<rows / 4, 256, 0, stream>>>(ch_tB, ch_tB, nullptr, mln2_g, mln2_b, rows);
        // z2 = relu(relu([hoLn,spLn]) @ m1 + b) -> ch_tA (rows x 384)
        bgemm(stream, ch_peh, nullptr, 256, wt + WT_M1,       512, m1_b,    ch_tA, 384, rows, 384, 256, false, false, true);
        bgemm(stream, ch_tB,  nullptr, 256, wt + WT_M1 + 256, 512, nullptr, ch_tA, 384, rows, 384, 256, true,  true,  true);
        // out chunk
        bgemm(stream, ch_tA, nullptr, 384, wt + WT_M2, 384, m2_b, out + c0 * 256, 256, rows, 256, 384, true, false, false);
    }
}

// Round 4
// 1232.251 us; speedup vs baseline: 11.3381x; 2.9340x over previous
//
#include <hip/hip_runtime.h>
#include <stdint.h>

// ---------------- problem dims (hard-coded from setup_inputs) ----------------
static constexpr int B      = 16;
static constexpr int N      = 128;
static constexpr int P      = 4064;     // 32*(128-1) kept pairs
static constexpr int MPOSE  = 64;
static constexpr int64_t BN = (int64_t)B * N;   // 2048
static constexpr int64_t BP = (int64_t)B * P;   // 65024 = 508*128

#define TWO_PI 6.283185307179586f
#define QSCALE 0.17677669529663687f  /* 1/sqrt(32) */

typedef __attribute__((ext_vector_type(4))) float f32x4;
typedef __attribute__((ext_vector_type(8))) short bf16x8;
typedef __attribute__((ext_vector_type(8))) unsigned short u16x8;

__device__ __forceinline__ unsigned short f2bf(float f) {
    union { float f; unsigned u; } v; v.f = f;
    unsigned r = (v.u + 0x7fffu + ((v.u >> 16) & 1u)) >> 16;   // RNE
    return (unsigned short)r;
}

__device__ __forceinline__ void pair_xy(int p, int& x, int& y) {
    x = p / 127;
    int r = p - x * 127;
    y = (r < x) ? r : r + 1;
}

// ---------------- weight prep: W[K][N] fp32 -> Wt[N][Kpad] bf16 (zero-pad K) ----------------
__global__ __launch_bounds__(256) void wprep_k(
    const float* __restrict__ W, int K, int Nn,
    unsigned short* __restrict__ Wt, int Kpad)
{
    __shared__ float s[32][33];
    int k0 = blockIdx.x * 32, n0 = blockIdx.y * 32;
    int tx = threadIdx.x & 31, ty = threadIdx.x >> 5;   // 32 x 8
#pragma unroll
    for (int i = 0; i < 4; ++i) {
        int k = k0 + ty + i * 8;
        s[ty + i * 8][tx] = (k < K) ? W[(int64_t)k * Nn + n0 + tx] : 0.f;
    }
    __syncthreads();
#pragma unroll
    for (int i = 0; i < 4; ++i) {
        int n = n0 + ty + i * 8;
        Wt[(int64_t)n * Kpad + k0 + tx] = f2bf(s[tx][ty + i * 8]);
    }
}

static void wprep(hipStream_t st, const float* W, int K, int Nn, unsigned short* Wt, int Kpad)
{
    dim3 g(Kpad / 32, Nn / 32);
    wprep_k<<<g, 256, 0, st>>>(W, K, Nn, Wt, Kpad);
}

// ---------------- bf16 MFMA GEMM: C = act( (A(+A2)) @ Wt^T + bias ) ----------------
// Tile 128x128, BK=32, 256 thr = 4 waves (2x2), per-wave 64x64 = 4x4 frags of 16x16x32.
template <bool RELU_OUT, bool ADD_C, bool RELU_A>
__global__ __launch_bounds__(256) void bgemm_k(
    const float* __restrict__ A, const float* __restrict__ A2, int lda,
    const unsigned short* __restrict__ Bt, int ldk,
    const float* __restrict__ bias,
    float* __restrict__ C, int ldc,
    int K, int kSteps)
{
    __shared__ unsigned short As[128][40];
    __shared__ unsigned short Bs[128][40];
    const int tid  = threadIdx.x;
    const int lane = tid & 63;
    const int wave = tid >> 6;
    const int wr = wave >> 1, wc = wave & 1;
    const int row0 = blockIdx.y * 128, col0 = blockIdx.x * 128;
    const int l15 = lane & 15, l4 = lane >> 4;
    const int sr = tid >> 1;
    const int sh = (tid & 1) * 16;

    f32x4 acc[4][4] = {};

    for (int ks = 0; ks < kSteps; ++ks) {
        const int k0 = ks * 32;
        {
            const int64_t off = (int64_t)(row0 + sr) * lda + k0 + sh;
            const float* ap = A + off;
            float v[16];
            if (k0 + sh + 16 <= K) {
#pragma unroll
                for (int i = 0; i < 4; ++i) {
                    float4 t = ((const float4*)ap)[i];
                    v[i*4+0] = t.x; v[i*4+1] = t.y; v[i*4+2] = t.z; v[i*4+3] = t.w;
                }
                if (A2) {
                    const float* ap2 = A2 + off;
#pragma unroll
                    for (int i = 0; i < 4; ++i) {
                        float4 t = ((const float4*)ap2)[i];
                        v[i*4+0] += t.x; v[i*4+1] += t.y; v[i*4+2] += t.z; v[i*4+3] += t.w;
                    }
                }
            } else {
#pragma unroll
                for (int j = 0; j < 16; ++j) {
                    int gk = k0 + sh + j;
                    float x = 0.f;
                    if (gk < K) {
                        x = ap[j];
                        if (A2) x += A2[off + j];
                    }
                    v[j] = x;
                }
            }
            if (RELU_A) {
#pragma unroll
                for (int j = 0; j < 16; ++j) v[j] = fmaxf(v[j], 0.f);
            }
            u16x8 p0, p1;
#pragma unroll
            for (int j = 0; j < 8; ++j) { p0[j] = f2bf(v[j]); p1[j] = f2bf(v[8 + j]); }
            *(u16x8*)&As[sr][sh]     = p0;
            *(u16x8*)&As[sr][sh + 8] = p1;
        }
        {
            const unsigned short* bp = Bt + (int64_t)(col0 + sr) * ldk + k0 + sh;
            u16x8 q0 = *(const u16x8*)bp;
            u16x8 q1 = *(const u16x8*)(bp + 8);
            *(u16x8*)&Bs[sr][sh]     = q0;
            *(u16x8*)&Bs[sr][sh + 8] = q1;
        }
        __syncthreads();
        bf16x8 af[4], bfr[4];
#pragma unroll
        for (int f = 0; f < 4; ++f) {
            af[f]  = *(const bf16x8*)&As[wr * 64 + f * 16 + l15][l4 * 8];
            bfr[f] = *(const bf16x8*)&Bs[wc * 64 + f * 16 + l15][l4 * 8];
        }
#pragma unroll
        for (int i = 0; i < 4; ++i)
#pragma unroll
            for (int j = 0; j < 4; ++j)
                acc[i][j] = __builtin_amdgcn_mfma_f32_16x16x32_bf16(af[i], bfr[j], acc[i][j], 0, 0, 0);
        __syncthreads();
    }
#pragma unroll
    for (int i = 0; i < 4; ++i) {
        int rb = row0 + wr * 64 + i * 16 + l4 * 4;
#pragma unroll
        for (int j = 0; j < 4; ++j) {
            int c = col0 + wc * 64 + j * 16 + l15;
            float bv = bias ? bias[c] : 0.f;
#pragma unroll
            for (int e = 0; e < 4; ++e) {
                int64_t off = (int64_t)(rb + e) * ldc + c;
                float vv = acc[i][j][e] + bv;
                if (ADD_C) vv += C[off];
                if (RELU_OUT) vv = fmaxf(vv, 0.f);
                C[off] = vv;
            }
        }
    }
}

static void bgemm(hipStream_t st,
                  const float* A, const float* A2, int lda,
                  const unsigned short* Bt, int ldk, const float* bias,
                  float* C, int ldc, int M, int Ncols, int K,
                  bool reluOut, bool addC, bool reluA)
{
    int kSteps = (K + 31) / 32;
    dim3 g(Ncols / 128, M / 128), b(256);
    if (!reluOut && !addC && !reluA)
        bgemm_k<false,false,false><<<g,b,0,st>>>(A,A2,lda,Bt,ldk,bias,C,ldc,K,kSteps);
    else if (reluOut && !addC && !reluA)
        bgemm_k<true,false,false><<<g,b,0,st>>>(A,A2,lda,Bt,ldk,bias,C,ldc,K,kSteps);
    else if (!reluOut && addC && !reluA)
        bgemm_k<false,true,false><<<g,b,0,st>>>(A,A2,lda,Bt,ldk,bias,C,ldc,K,kSteps);
    else if (!reluOut && !addC && reluA)
        bgemm_k<false,false,true><<<g,b,0,st>>>(A,A2,lda,Bt,ldk,bias,C,ldc,K,kSteps);
    else if (reluOut && addC && reluA)
        bgemm_k<true,true,true><<<g,b,0,st>>>(A,A2,lda,Bt,ldk,bias,C,ldc,K,kSteps);
    else
        bgemm_k<true,true,false><<<g,b,0,st>>>(A,A2,lda,Bt,ldk,bias,C,ldc,K,kSteps);
}

// ---------------- LayerNorm (D=256), optional residual, in-place safe ----------------
__global__ __launch_bounds__(256) void ln_k(
    float* __restrict__ out, const float* __restrict__ x, const float* __restrict__ res,
    const float* __restrict__ g, const float* __restrict__ be, int rows)
{
    int wave = threadIdx.x >> 6, lane = threadIdx.x & 63;
    int row = blockIdx.x * 4 + wave;
    if (row >= rows) return;
    int64_t base = (int64_t)row * 256 + lane * 4;
    float4 v = *(const float4*)(x + base);
    if (res) {
        float4 r = *(const float4*)(res + base);
        v.x += r.x; v.y += r.y; v.z += r.z; v.w += r.w;
    }
    float s  = v.x + v.y + v.z + v.w;
    float sq = v.x*v.x + v.y*v.y + v.z*v.z + v.w*v.w;
#pragma unroll
    for (int off = 1; off < 64; off <<= 1) {
        s  += __shfl_xor(s, off);
        sq += __shfl_xor(sq, off);
    }
    float m = s * (1.f/256.f);
    float var = sq * (1.f/256.f) - m * m;
    float inv = rsqrtf(var + 1e-5f);
    int c = lane * 4;
    float4 gg = *(const float4*)(g + c);
    float4 bb = *(const float4*)(be + c);
    float4 o;
    o.x = (v.x - m) * inv * gg.x + bb.x;
    o.y = (v.y - m) * inv * gg.y + bb.y;
    o.z = (v.z - m) * inv * gg.z + bb.z;
    o.w = (v.w - m) * inv * gg.w + bb.w;
    *(float4*)(out + base) = o;
}

// ---------------- pair-gather + LayerNorm: hoLn = LN(U[b,i] + V[b,j] + (bias in U)) ----------------
__global__ __launch_bounds__(256) void pairln_k(
    const float* __restrict__ U, const float* __restrict__ V,
    const float* __restrict__ g, const float* __restrict__ be,
    float* __restrict__ outp, int chunk0, int rows)
{
    int wave = threadIdx.x >> 6, lane = threadIdx.x & 63;
    int li = blockIdx.x * 4 + wave;
    if (li >= rows) return;
    int gp = chunk0 + li;
    int b = gp / P, p = gp - b * P;
    int xi, yi; pair_xy(p, xi, yi);
    int c = lane * 4;
    float4 u = *(const float4*)(U + ((int64_t)(b * 128 + xi)) * 256 + c);
    float4 vv = *(const float4*)(V + ((int64_t)(b * 128 + yi)) * 256 + c);
    float4 v;
    v.x = u.x + vv.x; v.y = u.y + vv.y; v.z = u.z + vv.z; v.w = u.w + vv.w;
    float s  = v.x + v.y + v.z + v.w;
    float sq = v.x*v.x + v.y*v.y + v.z*v.z + v.w*v.w;
#pragma unroll
    for (int off = 1; off < 64; off <<= 1) {
        s  += __shfl_xor(s, off);
        sq += __shfl_xor(sq, off);
    }
    float m = s * (1.f/256.f);
    float var = sq * (1.f/256.f) - m * m;
    float inv = rsqrtf(var + 1e-5f);
    float4 gg = *(const float4*)(g + c);
    float4 bb = *(const float4*)(be + c);
    float4 o;
    o.x = (v.x - m) * inv * gg.x + bb.x;
    o.y = (v.y - m) * inv * gg.y + bb.y;
    o.z = (v.z - m) * inv * gg.z + bb.z;
    o.w = (v.w - m) * inv * gg.w + bb.w;
    *(float4*)(outp + (int64_t)li * 256 + c) = o;
}

// ---------------- line: mean over 8x8, then proj (parallel over c-chunks) ----------------
__global__ __launch_bounds__(256) void line_mean_k(const float* __restrict__ line, float* __restrict__ lm)
{
    int wave = threadIdx.x >> 6, lane = threadIdx.x & 63;
    int bc = blockIdx.x * 4 + wave;
    float v = line[(int64_t)bc * 64 + lane];
#pragma unroll
    for (int off = 1; off < 64; off <<= 1) v += __shfl_xor(v, off);
    if (lane == 0) lm[bc] = v * (1.f/64.f);
}

__global__ __launch_bounds__(256) void line_proj_k(
    const float* __restrict__ lm, const float* __restrict__ lw,
    const float* __restrict__ lb, float* __restrict__ lf)
{
    __shared__ float red[8][32];
    int b = blockIdx.y, jg = blockIdx.x;
    int jj = threadIdx.x & 31, cc = threadIdx.x >> 5;
    int j = jg * 32 + jj;
    const float* lmb = lm + (int64_t)b * 2048 + cc * 256;
    const float* lwp = lw + (int64_t)(cc * 256) * 256 + j;
    float acc = 0.f;
#pragma unroll 4
    for (int k = 0; k < 256; ++k) acc += lmb[k] * lwp[(int64_t)k * 256];
    red[cc][jj] = acc;
    __syncthreads();
    if (cc == 0) {
        float s = lb[j];
#pragma unroll
        for (int i = 0; i < 8; ++i) s += red[i][jj];
        lf[b * 256 + j] = s;
    }
}

// ---------------- add line-feat broadcast: bpw[b,t,:] += lf[b,:] ----------------
__global__ __launch_bounds__(256) void add_lf_k(float* __restrict__ bpw, const float* __restrict__ lf)
{
    int r = blockIdx.x, c = threadIdx.x;
    bpw[(int64_t)r * 256 + c] += lf[(r >> 7) * 256 + c];
}

// ---------------- sinusoidal box PE ----------------
__global__ __launch_bounds__(512) void boxpe_k(
    const float* __restrict__ boxes, const float* __restrict__ sizes, float* __restrict__ boxpe)
{
    int row = blockIdx.x;
    int b = row >> 7;
    int i = threadIdx.x;
    const float* bx = boxes + (int64_t)row * 4;
    float h = sizes[b * 2 + 0], w = sizes[b * 2 + 1];
    float x0 = bx[0] / w, y0 = bx[1] / h, x1 = bx[2] / w, y1 = bx[3] / h;
    int seg = i >> 7, j = i & 127, k = j >> 1;
    float val;
    switch (seg) {
        case 0: val = (y0 + y1) * 0.5f; break;
        case 1: val = (x0 + x1) * 0.5f; break;
        case 2: val = (y1 - y0); break;
        default: val = (x1 - x0); break;
    }
    float dimt = powf(20.f, (float)k * (1.f/64.f));
    float arg = val * TWO_PI / dimt;
    boxpe[(int64_t)row * 512 + i] = (j & 1) ? cosf(arg) : sinf(arg);
}

// ---------------- spatial 36 features for a chunk of kept pairs ----------------
__global__ __launch_bounds__(256) void f36_k(
    const float* __restrict__ boxes, const float* __restrict__ sizes,
    float* __restrict__ f36, int chunk0, int cnt)
{
    int li = blockIdx.x * 256 + threadIdx.x;
    if (li >= cnt) return;
    int gp = chunk0 + li;
    int b = gp / P, p = gp - b * P;
    int xi, yi; pair_xy(p, xi, yi);
    const float* b1 = boxes + ((int64_t)b * N + xi) * 4;
    const float* b2 = boxes + ((int64_t)b * N + yi) * 4;
    float h = sizes[b * 2 + 0], w = sizes[b * 2 + 1];
    float c1x = (b1[0] + b1[2]) * 0.5f, c1y = (b1[1] + b1[3]) * 0.5f;
    float c2x = (b2[0] + b2[2]) * 0.5f, c2y = (b2[1] + b2[3]) * 0.5f;
    float w1 = b1[2] - b1[0], h1 = b1[3] - b1[1];
    float w2 = b2[2] - b2[0], h2 = b2[3] - b2[1];
    float a1 = w1 * h1, a2 = w2 * h2;
    float dx = fabsf(c2x - c1x) / (w1 + 1e-6f);
    float dy = fabsf(c2y - c1y) / (h1 + 1e-6f);
    float ix = fmaxf(fminf(b1[2], b2[2]) - fmaxf(b1[0], b2[0]), 0.f);
    float iy = fmaxf(fminf(b1[3], b2[3]) - fmaxf(b1[1], b2[1]), 0.f);
    float inter = ix * iy;
    float iou = inter / (a1 + a2 - inter + 1e-6f);
    float f[18];
    f[0] = c1x / w;  f[1] = c1y / h;  f[2] = c2x / w;  f[3] = c2y / h;
    f[4] = w1 / w;   f[5] = h1 / h;   f[6] = w2 / w;   f[7] = h2 / h;
    f[8] = a1 / (h * w); f[9] = a2 / (h * w); f[10] = a2 / (a1 + 1e-6f);
    f[11] = w1 / (h1 + 1e-6f); f[12] = w2 / (h2 + 1e-6f); f[13] = iou;
    f[14] = (c2x > c1x) ? dx : 0.f;  f[15] = (c2x < c1x) ? dx : 0.f;
    f[16] = (c2y > c1y) ? dy : 0.f;  f[17] = (c2y < c1y) ? dy : 0.f;
    float* o = f36 + (int64_t)li * 36;
#pragma unroll
    for (int i = 0; i < 18; ++i) {
        o[i] = f[i];
        o[18 + i] = logf(f[i] + 1e-6f);
    }
}

// ---------------- encoder self-attention (T=S=128, dh=32), per (b,head) block ----------------
__global__ __launch_bounds__(128) void enc_attn_k(
    const float* __restrict__ q, const float* __restrict__ k,
    const float* __restrict__ v, float* __restrict__ out)
{
    int b = blockIdx.x >> 3, hd = blockIdx.x & 7;
    __shared__ float kl[128][32];
    __shared__ float vl[128][32];
    int tid = threadIdx.x;
    for (int i = tid; i < 128 * 32; i += 128) {
        int s = i >> 5, j = i & 31;
        int64_t off = ((int64_t)b * N + s) * 256 + hd * 32 + j;
        kl[s][j] = k[off];
        vl[s][j] = v[off];
    }
    __syncthreads();
    int t = tid;
    int64_t qoff = ((int64_t)b * N + t) * 256 + hd * 32;
    float qr[32];
#pragma unroll
    for (int j = 0; j < 32; ++j) qr[j] = q[qoff + j] * QSCALE;
    float m = -1e30f, l = 0.f;
    for (int s = 0; s < 128; ++s) {
        float d = 0.f;
#pragma unroll
        for (int j = 0; j < 32; ++j) d += qr[j] * kl[s][j];
        float mn = fmaxf(m, d);
        l = l * __expf(m - mn) + __expf(d - mn);
        m = mn;
    }
    float acc[32] = {};
    for (int s = 0; s < 128; ++s) {
        float d = 0.f;
#pragma unroll
        for (int j = 0; j < 32; ++j) d += qr[j] * kl[s][j];
        float wgt = __expf(d - m);
#pragma unroll
        for (int j = 0; j < 32; ++j) acc[j] += wgt * vl[s][j];
    }
    float linv = 1.f / l;
#pragma unroll
    for (int j = 0; j < 32; ++j) out[qoff + j] = acc[j] * linv;
}

// ---------------- decoder cross-attention (S=64, dh=32); rpb = rows per batch ----------------
__global__ __launch_bounds__(256) void dec_attn_k(
    const float* __restrict__ q, const float* __restrict__ kp,
    const float* __restrict__ vp, float* __restrict__ out,
    int chunk0, int rows, int rpb)
{
    int hd = blockIdx.y;
    int r0 = blockIdx.x * 256;
    __shared__ float kl[2][64][32];
    __shared__ float vl[2][64][32];
    int tid = threadIdx.x;
    int b0 = (chunk0 + r0) / rpb;
    int b1 = (chunk0 + r0 + 255) / rpb;
    if (b1 >= B) b1 = B - 1;
    for (int i = tid; i < 64 * 32; i += 256) {
        int s = i >> 5, j = i & 31;
        int64_t off0 = ((int64_t)b0 * MPOSE + s) * 256 + hd * 32 + j;
        int64_t off1 = ((int64_t)b1 * MPOSE + s) * 256 + hd * 32 + j;
        kl[0][s][j] = kp[off0];
        vl[0][s][j] = vp[off0];
        kl[1][s][j] = kp[off1];
        vl[1][s][j] = vp[off1];
    }
    __syncthreads();
    int r = r0 + tid;
    if (r >= rows) return;
    int which = ((chunk0 + r) / rpb == b0) ? 0 : 1;
    int64_t qoff = (int64_t)r * 256 + hd * 32;
    float qr[32];
#pragma unroll
    for (int j = 0; j < 32; ++j) qr[j] = q[qoff + j] * QSCALE;
    float m = -1e30f, l = 0.f;
    for (int s = 0; s < 64; ++s) {
        float d = 0.f;
#pragma unroll
        for (int j = 0; j < 32; ++j) d += qr[j] * kl[which][s][j];
        float mn = fmaxf(m, d);
        l = l * __expf(m - mn) + __expf(d - mn);
        m = mn;
    }
    float acc[32] = {};
    for (int s = 0; s < 64; ++s) {
        float d = 0.f;
#pragma unroll
        for (int j = 0; j < 32; ++j) d += qr[j] * kl[which][s][j];
        float wgt = __expf(d - m);
#pragma unroll
        for (int j = 0; j < 32; ++j) acc[j] += wgt * vl[which][s][j];
    }
    float linv = 1.f / l;
#pragma unroll
    for (int j = 0; j < 32; ++j) out[qoff + j] = acc[j] * linv;
}

// ---------------- bf16 weight arena offsets (ushort units) ----------------
static constexpr int64_t WT_QKV  = 0;
static constexpr int64_t WT_EOUT = WT_QKV  + 2*196608;
static constexpr int64_t WT_EFF1 = WT_EOUT + 2*65536;
static constexpr int64_t WT_EFF2 = WT_EFF1 + 2*262144;
static constexpr int64_t WT_DQ   = WT_EFF2 + 2*262144;
static constexpr int64_t WT_DKV  = WT_DQ   + 2*65536;
static constexpr int64_t WT_DOUT = WT_DKV  + 2*131072;
static constexpr int64_t WT_DFF1 = WT_DOUT + 2*65536;
static constexpr int64_t WT_DFF2 = WT_DFF1 + 2*262144;
static constexpr int64_t WT_SW1  = WT_DFF2 + 2*262144;
static constexpr int64_t WT_SW2  = WT_SW1 + 8192;
static constexpr int64_t WT_SW3  = WT_SW2 + 32768;
static constexpr int64_t WT_BW   = WT_SW3 + 65536;
static constexpr int64_t WT_PW   = WT_BW  + 131072;
static constexpr int64_t WT_EPE  = WT_PW  + 196608;
static constexpr int64_t WT_FC1  = WT_EPE + 131072;
static constexpr int64_t WT_FC2  = WT_FC1 + 131072;
static constexpr int64_t WT_M1   = WT_FC2 + 65536;
static constexpr int64_t WT_M2   = WT_M1  + 196608;
static constexpr int64_t WT_TOTAL = WT_M2 + 98304;

// ---------------- host orchestration ----------------
extern "C" void kernel_launch(void* const* d_in, const int* in_sizes, int n_in,
                              void* d_out, int out_size, void* d_ws, size_t ws_size,
                              hipStream_t stream)
{
    (void)in_sizes; (void)n_in; (void)out_size;
    const float* boxes     = (const float*)d_in[0];
    const float* embeds    = (const float*)d_in[1];
    const float* sizes     = (const float*)d_in[2];
    const float* pose      = (const float*)d_in[3];
    const float* line      = (const float*)d_in[4];
    const float* sw1 = (const float*)d_in[5];  const float* sb1 = (const float*)d_in[6];
    const float* sw2 = (const float*)d_in[7];  const float* sb2 = (const float*)d_in[8];
    const float* sw3 = (const float*)d_in[9];  const float* sb3 = (const float*)d_in[10];
    const float* bw  = (const float*)d_in[11]; const float* bb  = (const float*)d_in[12];
    const float* pw  = (const float*)d_in[13]; const float* pb  = (const float*)d_in[14];
    const float* lw  = (const float*)d_in[15]; const float* lb  = (const float*)d_in[16];
    const float* enc_pe_w  = (const float*)d_in[17]; const float* enc_pe_b = (const float*)d_in[18];
    const float* enc_qkv_w = (const float*)d_in[19]; const float* enc_qkv_b = (const float*)d_in[20];
    const float* enc_out_w = (const float*)d_in[21]; const float* enc_out_b = (const float*)d_in[22];
    const float* enc_ff1_w = (const float*)d_in[23]; const float* enc_ff1_b = (const float*)d_in[24];
    const float* enc_ff2_w = (const float*)d_in[25]; const float* enc_ff2_b = (const float*)d_in[26];
    const float* enc_ln1_g = (const float*)d_in[27]; const float* enc_ln1_b = (const float*)d_in[28];
    const float* enc_ln2_g = (const float*)d_in[29]; const float* enc_ln2_b = (const float*)d_in[30];
    const float* dec_q_w   = (const float*)d_in[31]; const float* dec_q_b  = (const float*)d_in[32];
    const float* dec_kv_w  = (const float*)d_in[33]; const float* dec_kv_b = (const float*)d_in[34];
    const float* dec_out_w = (const float*)d_in[35]; const float* dec_out_b = (const float*)d_in[36];
    const float* dec_ff1_w = (const float*)d_in[37]; const float* dec_ff1_b = (const float*)d_in[38];
    const float* dec_ff2_w = (const float*)d_in[39]; const float* dec_ff2_b = (const float*)d_in[40];
    const float* dec_ln1_g = (const float*)d_in[41]; const float* dec_ln1_b = (const float*)d_in[42];
    const float* dec_ln2_g = (const float*)d_in[43]; const float* dec_ln2_b = (const float*)d_in[44];
    const float* fc1_w = (const float*)d_in[45]; const float* fc1_b = (const float*)d_in[46];
    const float* fc2_w = (const float*)d_in[47]; const float* fc2_b = (const float*)d_in[48];
    const float* mln1_g = (const float*)d_in[49]; const float* mln1_b = (const float*)d_in[50];
    const float* mln2_g = (const float*)d_in[51]; const float* mln2_b = (const float*)d_in[52];
    const float* m1_w = (const float*)d_in[53]; const float* m1_b = (const float*)d_in[54];
    const float* m2_w = (const float*)d_in[55]; const float* m2_b = (const float*)d_in[56];
    float* out = (float*)d_out;

    // ---- workspace layout (floats) ----
    float* base = (float*)d_ws;
    int64_t wsf = (int64_t)(ws_size / sizeof(float));
    float* x_   = base;                       // 524288 (tokens; becomes decoded tokens)
    float* bpw_ = x_   + 524288;              // 524288 (box_pe@bw+bb, then += lf -> pe_tok)
    float* lf   = bpw_ + 524288;              // 4096
    float* kv0  = lf   + 4096;                // 4 x 262144 (dec K/V; later U,V 2 x 524288)
    unsigned short* wt = (unsigned short*)(kv0 + 4 * 262144);
    float* arena = (float*)(wt + WT_TOTAL);
    const int64_t LIVE_F = arena - base;
    int64_t arena_f = wsf - LIVE_F;
    if (arena_f < 0) arena_f = 0;

    // setup-phase views into arena
    float* posx  = arena;                     // 524288
    float* boxpe = posx  + 524288;            // 1048576
    float* e_q   = boxpe + 1048576;
    float* e_k   = e_q   + 524288;
    float* e_v   = e_k   + 524288;
    float* e_t   = e_v   + 524288;
    float* e_ff  = e_t   + 524288;            // 2097152
    float* pctx  = e_ff  + 2097152;           // 262144
    float* lm    = pctx  + 262144;            // 32768

    // pair-chunk: per-row = pA 256 + pB 256 + pC 384 + pD 256 = 1152 floats
    int64_t rc = (arena_f / 1152) & ~127LL;
    if (rc > BP) rc = BP;
    if (rc < 128) rc = 128;

    // ---- stage 0: weight prep ----
    for (int i = 0; i < 2; ++i) {
        wprep(stream, enc_qkv_w + (int64_t)i*196608, 256, 768,  wt + WT_QKV  + i*196608, 256);
        wprep(stream, enc_out_w + (int64_t)i*65536,  256, 256,  wt + WT_EOUT + i*65536,  256);
        wprep(stream, enc_ff1_w + (int64_t)i*262144, 256, 1024, wt + WT_EFF1 + i*262144, 256);
        wprep(stream, enc_ff2_w + (int64_t)i*262144, 1024, 256, wt + WT_EFF2 + i*262144, 1024);
        wprep(stream, dec_q_w   + (int64_t)i*65536,  256, 256,  wt + WT_DQ   + i*65536,  256);
        wprep(stream, dec_kv_w  + (int64_t)i*131072, 256, 512,  wt + WT_DKV  + i*131072, 256);
        wprep(stream, dec_out_w + (int64_t)i*65536,  256, 256,  wt + WT_DOUT + i*65536,  256);
        wprep(stream, dec_ff1_w + (int64_t)i*262144, 256, 1024, wt + WT_DFF1 + i*262144, 256);
        wprep(stream, dec_ff2_w + (int64_t)i*262144, 1024, 256, wt + WT_DFF2 + i*262144, 1024);
    }
    wprep(stream, sw1, 36, 128,  wt + WT_SW1, 64);
    wprep(stream, sw2, 128, 256, wt + WT_SW2, 128);
    wprep(stream, sw3, 256, 256, wt + WT_SW3, 256);
    wprep(stream, bw,  512, 256, wt + WT_BW,  512);
    wprep(stream, pw,  768, 256, wt + WT_PW,  768);
    wprep(stream, enc_pe_w, 512, 256, wt + WT_EPE, 512);
    wprep(stream, fc1_w, 512, 256, wt + WT_FC1, 512);
    wprep(stream, fc2_w, 256, 256, wt + WT_FC2, 256);
    wprep(stream, m1_w, 512, 384, wt + WT_M1, 512);
    wprep(stream, m2_w, 384, 256, wt + WT_M2, 384);

    // ---- stage A: small precomputes ----
    line_mean_k<<<8192, 256, 0, stream>>>(line, lm);
    line_proj_k<<<dim3(8, B), 256, 0, stream>>>(lm, lw, lb, lf);
    boxpe_k<<<(int)BN, 512, 0, stream>>>(boxes, sizes, boxpe);
    bgemm(stream, boxpe, nullptr, 512, wt + WT_EPE, 512, enc_pe_b, posx, 256, (int)BN, 256, 512, false, false, false);
    bgemm(stream, boxpe, nullptr, 512, wt + WT_BW,  512, bb,       bpw_, 256, (int)BN, 256, 512, false, false, false);
    bgemm(stream, pose,  nullptr, 768, wt + WT_PW,  768, pb,       pctx, 256, B*MPOSE, 256, 768, false, false, false);
    for (int l = 0; l < 2; ++l) {
        const float* bkv = dec_kv_b + (int64_t)l * 512;
        bgemm(stream, pctx, nullptr, 256, wt + WT_DKV + l*131072,         256, bkv,       kv0 + (2*l+0)*262144, 256, B*MPOSE, 256, 256, false, false, false);
        bgemm(stream, pctx, nullptr, 256, wt + WT_DKV + l*131072 + 65536, 256, bkv + 256, kv0 + (2*l+1)*262144, 256, B*MPOSE, 256, 256, false, false, false);
    }

    // ---- stage B: encoder (2 layers) on x_ (2048 tokens) ----
    hipMemcpyAsync(x_, embeds, BN * 256 * sizeof(float), hipMemcpyDeviceToDevice, stream);
    for (int i = 0; i < 2; ++i) {
        const unsigned short* Wq = wt + WT_QKV + (int64_t)i * 196608;
        const float* bqkv = enc_qkv_b + (int64_t)i * 768;
        bgemm(stream, x_, posx, 256, Wq,          256, bqkv,       e_q, 256, (int)BN, 256, 256, false, false, false);
        bgemm(stream, x_, posx, 256, Wq + 65536,  256, bqkv + 256, e_k, 256, (int)BN, 256, 256, false, false, false);
        bgemm(stream, x_, nullptr, 256, Wq + 131072, 256, bqkv + 512, e_v, 256, (int)BN, 256, 256, false, false, false);
        enc_attn_k<<<B * 8, 128, 0, stream>>>(e_q, e_k, e_v, e_t);
        bgemm(stream, e_t, nullptr, 256, wt + WT_EOUT + (int64_t)i*65536, 256, enc_out_b + i * 256,
              e_q, 256, (int)BN, 256, 256, false, false, false);
        ln_k<<<(int)(BN / 4), 256, 0, stream>>>(x_, x_, e_q, enc_ln1_g + i * 256, enc_ln1_b + i * 256, (int)BN);
        bgemm(stream, x_, nullptr, 256, wt + WT_EFF1 + (int64_t)i*262144, 256, enc_ff1_b + i * 1024,
              e_ff, 1024, (int)BN, 1024, 256, true, false, false);
        bgemm(stream, e_ff, nullptr, 1024, wt + WT_EFF2 + (int64_t)i*262144, 1024, enc_ff2_b + i * 256,
              e_t, 256, (int)BN, 256, 1024, false, false, false);
        ln_k<<<(int)(BN / 4), 256, 0, stream>>>(x_, x_, e_t, enc_ln2_g + i * 256, enc_ln2_b + i * 256, (int)BN);
    }

    // ---- stage C: decoder on DISTINCT rows = all 2048 tokens (h/o streams collapse) ----
    add_lf_k<<<(int)BN, 256, 0, stream>>>(bpw_, lf);   // pe_tok = box_pe@bw + bb + lf
    for (int l = 0; l < 2; ++l) {
        const float* kp = kv0 + (2*l+0)*262144;
        const float* vp = kv0 + (2*l+1)*262144;
        bgemm(stream, x_, bpw_, 256, wt + WT_DQ + (int64_t)l*65536, 256, dec_q_b + l * 256,
              e_q, 256, (int)BN, 256, 256, false, false, false);
        dec_attn_k<<<dim3((int)(BN / 256), 8), 256, 0, stream>>>(e_q, kp, vp, e_t, 0, (int)BN, N);
        bgemm(stream, e_t, nullptr, 256, wt + WT_DOUT + (int64_t)l*65536, 256, dec_out_b + l * 256,
              e_q, 256, (int)BN, 256, 256, false, false, false);
        ln_k<<<(int)(BN / 4), 256, 0, stream>>>(x_, x_, e_q, dec_ln1_g + l * 256, dec_ln1_b + l * 256, (int)BN);
        bgemm(stream, x_, nullptr, 256, wt + WT_DFF1 + (int64_t)l*262144, 256, dec_ff1_b + l * 1024,
              e_ff, 1024, (int)BN, 1024, 256, true, false, false);
        bgemm(stream, e_ff, nullptr, 1024, wt + WT_DFF2 + (int64_t)l*262144, 1024, dec_ff2_b + l * 256,
              e_t, 256, (int)BN, 256, 1024, false, false, false);
        ln_k<<<(int)(BN / 4), 256, 0, stream>>>(x_, x_, e_t, dec_ln2_g + l * 256, dec_ln2_b + l * 256, (int)BN);
    }
    // U = y@fc1_top + fc1_b, V = y@fc1_bot  (kv dead -> reuse kv0)
    float* U = kv0;
    float* V = kv0 + 524288;
    bgemm(stream, x_, nullptr, 256, wt + WT_FC1,       512, fc1_b,   U, 256, (int)BN, 256, 256, false, false, false);
    bgemm(stream, x_, nullptr, 256, wt + WT_FC1 + 256, 512, nullptr, V, 256, (int)BN, 256, 256, false, false, false);

    // ---- stage D: per-pair head, chunked ----
    for (int64_t c0 = 0; c0 < BP; c0 += rc) {
        int rows = (int)((BP - c0 < rc) ? (BP - c0) : rc);   // multiple of 128
        float* pA = arena;                       // 256/row (hoLn; also spa-mlp t1 at 128)
        float* pB = pA + (int64_t)rc * 256;      // 256/row (spLn / tmp)
        float* pC = pB + (int64_t)rc * 256;      // 384/row (z2)
        float* pD = pC + (int64_t)rc * 384;      // 256/row (f36 @36 / spa)

        // spatial MLP
        f36_k<<<(rows + 255) / 256, 256, 0, stream>>>(boxes, sizes, pD, (int)c0, rows);
        bgemm(stream, pD, nullptr, 36,  wt + WT_SW1, 64,  sb1, pA, 128, rows, 128, 36,  true, false, false);
        bgemm(stream, pA, nullptr, 128, wt + WT_SW2, 128, sb2, pB, 256, rows, 256, 128, true, false, false);
        bgemm(stream, pB, nullptr, 256, wt + WT_SW3, 256, sb3, pD, 256, rows, 256, 256, true, false, false);
        bgemm(stream, pD, nullptr, 256, wt + WT_FC2, 256, fc2_b, pB, 256, rows, 256, 256, false, false, false);
        ln_k<<<rows / 4, 256, 0, stream>>>(pB, pB, nullptr, mln2_g, mln2_b, rows);      // spLn
        // hoLn = LN(U[b,i] + V[b,j])
        pairln_k<<<rows / 4, 256, 0, stream>>>(U, V, mln1_g, mln1_b, pA, (int)c0, rows);
        // z2 = relu(relu([hoLn,spLn]) @ m1 + m1_b)
        bgemm(stream, pA, nullptr, 256, wt + WT_M1,       512, m1_b,    pC, 384, rows, 384, 256, false, false, true);
        bgemm(stream, pB, nullptr, 256, wt + WT_M1 + 256, 512, nullptr, pC, 384, rows, 384, 256, true,  true,  true);
        // out = relu(z2 @ m2 + m2_b)
        bgemm(stream, pC, nullptr, 384, wt + WT_M2, 384, m2_b, out + c0 * 256, 256, rows, 256, 384, true, false, false);
    }
}

// Round 5
// 1030.951 us; speedup vs baseline: 13.5519x; 1.1953x over previous
//
#include <hip/hip_runtime.h>
#include <stdint.h>

// ---------------- problem dims (hard-coded from setup_inputs) ----------------
static constexpr int B      = 16;
static constexpr int N      = 128;
static constexpr int P      = 4064;     // 32*(128-1) kept pairs
static constexpr int MPOSE  = 64;
static constexpr int64_t BN = (int64_t)B * N;   // 2048
static constexpr int64_t BP = (int64_t)B * P;   // 65024 = 508*128

#define TWO_PI 6.283185307179586f
#define QSCALE 0.17677669529663687f  /* 1/sqrt(32) */

typedef __attribute__((ext_vector_type(4))) float f32x4;
typedef __attribute__((ext_vector_type(8))) short bf16x8;
typedef __attribute__((ext_vector_type(8))) unsigned short u16x8;
typedef __attribute__((ext_vector_type(4))) unsigned short u16x4;

__device__ __forceinline__ unsigned short f2bf(float f) {
    union { float f; unsigned u; } v; v.f = f;
    unsigned r = (v.u + 0x7fffu + ((v.u >> 16) & 1u)) >> 16;   // RNE
    return (unsigned short)r;
}
__device__ __forceinline__ float bf2f(unsigned short u) {
    union { unsigned u; float f; } v; v.u = (unsigned)u << 16;
    return v.f;
}

__device__ __forceinline__ void pair_xy(int p, int& x, int& y) {
    x = p / 127;
    int r = p - x * 127;
    y = (r < x) ? r : r + 1;
}

// ---------------- weight prep: W[K][N] fp32 -> Wt[N][Kpad] bf16 (zero-pad K) ----------------
__global__ __launch_bounds__(256) void wprep_k(
    const float* __restrict__ W, int K, int Nn,
    unsigned short* __restrict__ Wt, int Kpad)
{
    __shared__ float s[32][33];
    int k0 = blockIdx.x * 32, n0 = blockIdx.y * 32;
    int tx = threadIdx.x & 31, ty = threadIdx.x >> 5;   // 32 x 8
#pragma unroll
    for (int i = 0; i < 4; ++i) {
        int k = k0 + ty + i * 8;
        s[ty + i * 8][tx] = (k < K) ? W[(int64_t)k * Nn + n0 + tx] : 0.f;
    }
    __syncthreads();
#pragma unroll
    for (int i = 0; i < 4; ++i) {
        int n = n0 + ty + i * 8;
        Wt[(int64_t)n * Kpad + k0 + tx] = f2bf(s[tx][ty + i * 8]);
    }
}

static void wprep(hipStream_t st, const float* W, int K, int Nn, unsigned short* Wt, int Kpad)
{
    dim3 g(Kpad / 32, Nn / 32);
    wprep_k<<<g, 256, 0, st>>>(W, K, Nn, Wt, Kpad);
}

// ---------------- fp32-A bf16 MFMA GEMM (token stages): C = act( (A(+A2)) @ Wt^T + bias ) ----------------
template <bool RELU_OUT, bool ADD_C, bool RELU_A>
__global__ __launch_bounds__(256) void bgemm_k(
    const float* __restrict__ A, const float* __restrict__ A2, int lda,
    const unsigned short* __restrict__ Bt, int ldk,
    const float* __restrict__ bias,
    float* __restrict__ C, int ldc,
    int K, int kSteps)
{
    __shared__ unsigned short As[128][40];
    __shared__ unsigned short Bs[128][40];
    const int tid  = threadIdx.x;
    const int lane = tid & 63;
    const int wave = tid >> 6;
    const int wr = wave >> 1, wc = wave & 1;
    const int row0 = blockIdx.y * 128, col0 = blockIdx.x * 128;
    const int l15 = lane & 15, l4 = lane >> 4;
    const int sr = tid >> 1;
    const int sh = (tid & 1) * 16;

    f32x4 acc[4][4] = {};

    for (int ks = 0; ks < kSteps; ++ks) {
        const int k0 = ks * 32;
        {
            const int64_t off = (int64_t)(row0 + sr) * lda + k0 + sh;
            const float* ap = A + off;
            float v[16];
            if (k0 + sh + 16 <= K) {
#pragma unroll
                for (int i = 0; i < 4; ++i) {
                    float4 t = ((const float4*)ap)[i];
                    v[i*4+0] = t.x; v[i*4+1] = t.y; v[i*4+2] = t.z; v[i*4+3] = t.w;
                }
                if (A2) {
                    const float* ap2 = A2 + off;
#pragma unroll
                    for (int i = 0; i < 4; ++i) {
                        float4 t = ((const float4*)ap2)[i];
                        v[i*4+0] += t.x; v[i*4+1] += t.y; v[i*4+2] += t.z; v[i*4+3] += t.w;
                    }
                }
            } else {
#pragma unroll
                for (int j = 0; j < 16; ++j) {
                    int gk = k0 + sh + j;
                    float x = 0.f;
                    if (gk < K) {
                        x = ap[j];
                        if (A2) x += A2[off + j];
                    }
                    v[j] = x;
                }
            }
            if (RELU_A) {
#pragma unroll
                for (int j = 0; j < 16; ++j) v[j] = fmaxf(v[j], 0.f);
            }
            u16x8 p0, p1;
#pragma unroll
            for (int j = 0; j < 8; ++j) { p0[j] = f2bf(v[j]); p1[j] = f2bf(v[8 + j]); }
            *(u16x8*)&As[sr][sh]     = p0;
            *(u16x8*)&As[sr][sh + 8] = p1;
        }
        {
            const unsigned short* bp = Bt + (int64_t)(col0 + sr) * ldk + k0 + sh;
            u16x8 q0 = *(const u16x8*)bp;
            u16x8 q1 = *(const u16x8*)(bp + 8);
            *(u16x8*)&Bs[sr][sh]     = q0;
            *(u16x8*)&Bs[sr][sh + 8] = q1;
        }
        __syncthreads();
        bf16x8 af[4], bfr[4];
#pragma unroll
        for (int f = 0; f < 4; ++f) {
            af[f]  = *(const bf16x8*)&As[wr * 64 + f * 16 + l15][l4 * 8];
            bfr[f] = *(const bf16x8*)&Bs[wc * 64 + f * 16 + l15][l4 * 8];
        }
#pragma unroll
        for (int i = 0; i < 4; ++i)
#pragma unroll
            for (int j = 0; j < 4; ++j)
                acc[i][j] = __builtin_amdgcn_mfma_f32_16x16x32_bf16(af[i], bfr[j], acc[i][j], 0, 0, 0);
        __syncthreads();
    }
#pragma unroll
    for (int i = 0; i < 4; ++i) {
        int rb = row0 + wr * 64 + i * 16 + l4 * 4;
#pragma unroll
        for (int j = 0; j < 4; ++j) {
            int c = col0 + wc * 64 + j * 16 + l15;
            float bv = bias ? bias[c] : 0.f;
#pragma unroll
            for (int e = 0; e < 4; ++e) {
                int64_t off = (int64_t)(rb + e) * ldc + c;
                float vv = acc[i][j][e] + bv;
                if (ADD_C) vv += C[off];
                if (RELU_OUT) vv = fmaxf(vv, 0.f);
                C[off] = vv;
            }
        }
    }
}

static void bgemm(hipStream_t st,
                  const float* A, const float* A2, int lda,
                  const unsigned short* Bt, int ldk, const float* bias,
                  float* C, int ldc, int M, int Ncols, int K,
                  bool reluOut, bool addC, bool reluA)
{
    int kSteps = (K + 31) / 32;
    dim3 g(Ncols / 128, M / 128), b(256);
    if (!reluOut && !addC && !reluA)
        bgemm_k<false,false,false><<<g,b,0,st>>>(A,A2,lda,Bt,ldk,bias,C,ldc,K,kSteps);
    else if (reluOut && !addC && !reluA)
        bgemm_k<true,false,false><<<g,b,0,st>>>(A,A2,lda,Bt,ldk,bias,C,ldc,K,kSteps);
    else if (!reluOut && addC && !reluA)
        bgemm_k<false,true,false><<<g,b,0,st>>>(A,A2,lda,Bt,ldk,bias,C,ldc,K,kSteps);
    else
        bgemm_k<true,false,false><<<g,b,0,st>>>(A,A2,lda,Bt,ldk,bias,C,ldc,K,kSteps);
}

// ---------------- bf16-A MFMA GEMM (pair stages): C = act( A @ Wt^T + bias ) ----------------
// A bf16 [M][lda], lda%32==0, rows zero-padded to lda >= kSteps*32. Optional relu on A
// (exact: bf16 sign-bit mask). C written bf16 (OUT_BF16) or fp32.
template <bool RELU_OUT, bool RELU_A, bool OUT_BF16>
__global__ __launch_bounds__(256) void hgemm_k(
    const unsigned short* __restrict__ A, int lda,
    const unsigned short* __restrict__ Bt, int ldk,
    const float* __restrict__ bias,
    void* __restrict__ Cv, int ldc,
    int kSteps)
{
    __shared__ unsigned short As[128][40];
    __shared__ unsigned short Bs[128][40];
    const int tid  = threadIdx.x;
    const int lane = tid & 63;
    const int wave = tid >> 6;
    const int wr = wave >> 1, wc = wave & 1;
    const int row0 = blockIdx.y * 128, col0 = blockIdx.x * 128;
    const int l15 = lane & 15, l4 = lane >> 4;
    const int sr = tid >> 1;
    const int sh = (tid & 1) * 16;

    f32x4 acc[4][4] = {};

    for (int ks = 0; ks < kSteps; ++ks) {
        const int k0 = ks * 32;
        {
            const unsigned short* ap = A + (int64_t)(row0 + sr) * lda + k0 + sh;
            u16x8 q0 = *(const u16x8*)ap;
            u16x8 q1 = *(const u16x8*)(ap + 8);
            if (RELU_A) {
#pragma unroll
                for (int j = 0; j < 8; ++j) {
                    q0[j] = (q0[j] & 0x8000u) ? 0 : q0[j];
                    q1[j] = (q1[j] & 0x8000u) ? 0 : q1[j];
                }
            }
            *(u16x8*)&As[sr][sh]     = q0;
            *(u16x8*)&As[sr][sh + 8] = q1;
        }
        {
            const unsigned short* bp = Bt + (int64_t)(col0 + sr) * ldk + k0 + sh;
            u16x8 q0 = *(const u16x8*)bp;
            u16x8 q1 = *(const u16x8*)(bp + 8);
            *(u16x8*)&Bs[sr][sh]     = q0;
            *(u16x8*)&Bs[sr][sh + 8] = q1;
        }
        __syncthreads();
        bf16x8 af[4], bfr[4];
#pragma unroll
        for (int f = 0; f < 4; ++f) {
            af[f]  = *(const bf16x8*)&As[wr * 64 + f * 16 + l15][l4 * 8];
            bfr[f] = *(const bf16x8*)&Bs[wc * 64 + f * 16 + l15][l4 * 8];
        }
#pragma unroll
        for (int i = 0; i < 4; ++i)
#pragma unroll
            for (int j = 0; j < 4; ++j)
                acc[i][j] = __builtin_amdgcn_mfma_f32_16x16x32_bf16(af[i], bfr[j], acc[i][j], 0, 0, 0);
        __syncthreads();
    }
#pragma unroll
    for (int i = 0; i < 4; ++i) {
        int rb = row0 + wr * 64 + i * 16 + l4 * 4;
#pragma unroll
        for (int j = 0; j < 4; ++j) {
            int c = col0 + wc * 64 + j * 16 + l15;
            float bv = bias ? bias[c] : 0.f;
#pragma unroll
            for (int e = 0; e < 4; ++e) {
                int64_t off = (int64_t)(rb + e) * ldc + c;
                float vv = acc[i][j][e] + bv;
                if (RELU_OUT) vv = fmaxf(vv, 0.f);
                if (OUT_BF16) ((unsigned short*)Cv)[off] = f2bf(vv);
                else          ((float*)Cv)[off] = vv;
            }
        }
    }
}

static void hgemm(hipStream_t st,
                  const unsigned short* A, int lda,
                  const unsigned short* Bt, int ldk, const float* bias,
                  void* C, int ldc, int M, int Ncols, int K,
                  bool reluOut, bool reluA, bool outBf16)
{
    int kSteps = (K + 31) / 32;
    dim3 g(Ncols / 128, M / 128), b(256);
    if (outBf16) {
        if (reluOut && reluA)       hgemm_k<true,true,true><<<g,b,0,st>>>(A,lda,Bt,ldk,bias,C,ldc,kSteps);
        else if (reluOut)           hgemm_k<true,false,true><<<g,b,0,st>>>(A,lda,Bt,ldk,bias,C,ldc,kSteps);
        else if (reluA)             hgemm_k<false,true,true><<<g,b,0,st>>>(A,lda,Bt,ldk,bias,C,ldc,kSteps);
        else                        hgemm_k<false,false,true><<<g,b,0,st>>>(A,lda,Bt,ldk,bias,C,ldc,kSteps);
    } else {
        if (reluOut && reluA)       hgemm_k<true,true,false><<<g,b,0,st>>>(A,lda,Bt,ldk,bias,C,ldc,kSteps);
        else if (reluOut)           hgemm_k<true,false,false><<<g,b,0,st>>>(A,lda,Bt,ldk,bias,C,ldc,kSteps);
        else if (reluA)             hgemm_k<false,true,false><<<g,b,0,st>>>(A,lda,Bt,ldk,bias,C,ldc,kSteps);
        else                        hgemm_k<false,false,false><<<g,b,0,st>>>(A,lda,Bt,ldk,bias,C,ldc,kSteps);
    }
}

// ---------------- LayerNorm fp32 (D=256), optional residual ----------------
__global__ __launch_bounds__(256) void ln_k(
    float* __restrict__ out, const float* __restrict__ x, const float* __restrict__ res,
    const float* __restrict__ g, const float* __restrict__ be, int rows)
{
    int wave = threadIdx.x >> 6, lane = threadIdx.x & 63;
    int row = blockIdx.x * 4 + wave;
    if (row >= rows) return;
    int64_t base = (int64_t)row * 256 + lane * 4;
    float4 v = *(const float4*)(x + base);
    if (res) {
        float4 r = *(const float4*)(res + base);
        v.x += r.x; v.y += r.y; v.z += r.z; v.w += r.w;
    }
    float s  = v.x + v.y + v.z + v.w;
    float sq = v.x*v.x + v.y*v.y + v.z*v.z + v.w*v.w;
#pragma unroll
    for (int off = 1; off < 64; off <<= 1) {
        s  += __shfl_xor(s, off);
        sq += __shfl_xor(sq, off);
    }
    float m = s * (1.f/256.f);
    float var = sq * (1.f/256.f) - m * m;
    float inv = rsqrtf(var + 1e-5f);
    int c = lane * 4;
    float4 gg = *(const float4*)(g + c);
    float4 bb = *(const float4*)(be + c);
    float4 o;
    o.x = (v.x - m) * inv * gg.x + bb.x;
    o.y = (v.y - m) * inv * gg.y + bb.y;
    o.z = (v.z - m) * inv * gg.z + bb.z;
    o.w = (v.w - m) * inv * gg.w + bb.w;
    *(float4*)(out + base) = o;
}

// ---------------- LayerNorm bf16 in -> bf16 out at stride ldo (spLn into z[:,256:512]) ----------------
__global__ __launch_bounds__(256) void lnh_k(
    unsigned short* __restrict__ outp, int ldo,
    const unsigned short* __restrict__ x, int ldx,
    const float* __restrict__ g, const float* __restrict__ be, int rows)
{
    int wave = threadIdx.x >> 6, lane = threadIdx.x & 63;
    int row = blockIdx.x * 4 + wave;
    if (row >= rows) return;
    u16x4 u = *(const u16x4*)(x + (int64_t)row * ldx + lane * 4);
    float4 v;
    v.x = bf2f(u[0]); v.y = bf2f(u[1]); v.z = bf2f(u[2]); v.w = bf2f(u[3]);
    float s  = v.x + v.y + v.z + v.w;
    float sq = v.x*v.x + v.y*v.y + v.z*v.z + v.w*v.w;
#pragma unroll
    for (int off = 1; off < 64; off <<= 1) {
        s  += __shfl_xor(s, off);
        sq += __shfl_xor(sq, off);
    }
    float m = s * (1.f/256.f);
    float var = sq * (1.f/256.f) - m * m;
    float inv = rsqrtf(var + 1e-5f);
    int c = lane * 4;
    float4 gg = *(const float4*)(g + c);
    float4 bb = *(const float4*)(be + c);
    u16x4 o;
    o[0] = f2bf((v.x - m) * inv * gg.x + bb.x);
    o[1] = f2bf((v.y - m) * inv * gg.y + bb.y);
    o[2] = f2bf((v.z - m) * inv * gg.z + bb.z);
    o[3] = f2bf((v.w - m) * inv * gg.w + bb.w);
    *(u16x4*)(outp + (int64_t)row * ldo + c) = o;
}

// ---------------- pair-gather + LN: z[:,0:256] = LN(U[b,i] + V[b,j]) in bf16 ----------------
__global__ __launch_bounds__(256) void pairln_k(
    const float* __restrict__ U, const float* __restrict__ V,
    const float* __restrict__ g, const float* __restrict__ be,
    unsigned short* __restrict__ outp, int ldo, int chunk0, int rows)
{
    int wave = threadIdx.x >> 6, lane = threadIdx.x & 63;
    int li = blockIdx.x * 4 + wave;
    if (li >= rows) return;
    int gp = chunk0 + li;
    int b = gp / P, p = gp - b * P;
    int xi, yi; pair_xy(p, xi, yi);
    int c = lane * 4;
    float4 u = *(const float4*)(U + ((int64_t)(b * 128 + xi)) * 256 + c);
    float4 vv = *(const float4*)(V + ((int64_t)(b * 128 + yi)) * 256 + c);
    float4 v;
    v.x = u.x + vv.x; v.y = u.y + vv.y; v.z = u.z + vv.z; v.w = u.w + vv.w;
    float s  = v.x + v.y + v.z + v.w;
    float sq = v.x*v.x + v.y*v.y + v.z*v.z + v.w*v.w;
#pragma unroll
    for (int off = 1; off < 64; off <<= 1) {
        s  += __shfl_xor(s, off);
        sq += __shfl_xor(sq, off);
    }
    float m = s * (1.f/256.f);
    float var = sq * (1.f/256.f) - m * m;
    float inv = rsqrtf(var + 1e-5f);
    float4 gg = *(const float4*)(g + c);
    float4 bb = *(const float4*)(be + c);
    u16x4 o;
    o[0] = f2bf((v.x - m) * inv * gg.x + bb.x);
    o[1] = f2bf((v.y - m) * inv * gg.y + bb.y);
    o[2] = f2bf((v.z - m) * inv * gg.z + bb.z);
    o[3] = f2bf((v.w - m) * inv * gg.w + bb.w);
    *(u16x4*)(outp + (int64_t)li * ldo + c) = o;
}

// ---------------- line: mean over 8x8, then proj ----------------
__global__ __launch_bounds__(256) void line_mean_k(const float* __restrict__ line, float* __restrict__ lm)
{
    int wave = threadIdx.x >> 6, lane = threadIdx.x & 63;
    int bc = blockIdx.x * 4 + wave;
    float v = line[(int64_t)bc * 64 + lane];
#pragma unroll
    for (int off = 1; off < 64; off <<= 1) v += __shfl_xor(v, off);
    if (lane == 0) lm[bc] = v * (1.f/64.f);
}

__global__ __launch_bounds__(256) void line_proj_k(
    const float* __restrict__ lm, const float* __restrict__ lw,
    const float* __restrict__ lb, float* __restrict__ lf)
{
    __shared__ float red[8][32];
    int b = blockIdx.y, jg = blockIdx.x;
    int jj = threadIdx.x & 31, cc = threadIdx.x >> 5;
    int j = jg * 32 + jj;
    const float* lmb = lm + (int64_t)b * 2048 + cc * 256;
    const float* lwp = lw + (int64_t)(cc * 256) * 256 + j;
    float acc = 0.f;
#pragma unroll 4
    for (int k = 0; k < 256; ++k) acc += lmb[k] * lwp[(int64_t)k * 256];
    red[cc][jj] = acc;
    __syncthreads();
    if (cc == 0) {
        float s = lb[j];
#pragma unroll
        for (int i = 0; i < 8; ++i) s += red[i][jj];
        lf[b * 256 + j] = s;
    }
}

// ---------------- add line-feat broadcast ----------------
__global__ __launch_bounds__(256) void add_lf_k(float* __restrict__ bpw, const float* __restrict__ lf)
{
    int r = blockIdx.x, c = threadIdx.x;
    bpw[(int64_t)r * 256 + c] += lf[(r >> 7) * 256 + c];
}

// ---------------- sinusoidal box PE ----------------
__global__ __launch_bounds__(512) void boxpe_k(
    const float* __restrict__ boxes, const float* __restrict__ sizes, float* __restrict__ boxpe)
{
    int row = blockIdx.x;
    int b = row >> 7;
    int i = threadIdx.x;
    const float* bx = boxes + (int64_t)row * 4;
    float h = sizes[b * 2 + 0], w = sizes[b * 2 + 1];
    float x0 = bx[0] / w, y0 = bx[1] / h, x1 = bx[2] / w, y1 = bx[3] / h;
    int seg = i >> 7, j = i & 127, k = j >> 1;
    float val;
    switch (seg) {
        case 0: val = (y0 + y1) * 0.5f; break;
        case 1: val = (x0 + x1) * 0.5f; break;
        case 2: val = (y1 - y0); break;
        default: val = (x1 - x0); break;
    }
    float dimt = powf(20.f, (float)k * (1.f/64.f));
    float arg = val * TWO_PI / dimt;
    boxpe[(int64_t)row * 512 + i] = (j & 1) ? cosf(arg) : sinf(arg);
}

// ---------------- spatial 36 features -> bf16, rows padded to 64 ----------------
__global__ __launch_bounds__(256) void f36_k(
    const float* __restrict__ boxes, const float* __restrict__ sizes,
    unsigned short* __restrict__ f36, int chunk0, int cnt)
{
    int li = blockIdx.x * 256 + threadIdx.x;
    if (li >= cnt) return;
    int gp = chunk0 + li;
    int b = gp / P, p = gp - b * P;
    int xi, yi; pair_xy(p, xi, yi);
    const float* b1 = boxes + ((int64_t)b * N + xi) * 4;
    const float* b2 = boxes + ((int64_t)b * N + yi) * 4;
    float h = sizes[b * 2 + 0], w = sizes[b * 2 + 1];
    float c1x = (b1[0] + b1[2]) * 0.5f, c1y = (b1[1] + b1[3]) * 0.5f;
    float c2x = (b2[0] + b2[2]) * 0.5f, c2y = (b2[1] + b2[3]) * 0.5f;
    float w1 = b1[2] - b1[0], h1 = b1[3] - b1[1];
    float w2 = b2[2] - b2[0], h2 = b2[3] - b2[1];
    float a1 = w1 * h1, a2 = w2 * h2;
    float dx = fabsf(c2x - c1x) / (w1 + 1e-6f);
    float dy = fabsf(c2y - c1y) / (h1 + 1e-6f);
    float ix = fmaxf(fminf(b1[2], b2[2]) - fmaxf(b1[0], b2[0]), 0.f);
    float iy = fmaxf(fminf(b1[3], b2[3]) - fmaxf(b1[1], b2[1]), 0.f);
    float inter = ix * iy;
    float iou = inter / (a1 + a2 - inter + 1e-6f);
    float f[18];
    f[0] = c1x / w;  f[1] = c1y / h;  f[2] = c2x / w;  f[3] = c2y / h;
    f[4] = w1 / w;   f[5] = h1 / h;   f[6] = w2 / w;   f[7] = h2 / h;
    f[8] = a1 / (h * w); f[9] = a2 / (h * w); f[10] = a2 / (a1 + 1e-6f);
    f[11] = w1 / (h1 + 1e-6f); f[12] = w2 / (h2 + 1e-6f); f[13] = iou;
    f[14] = (c2x > c1x) ? dx : 0.f;  f[15] = (c2x < c1x) ? dx : 0.f;
    f[16] = (c2y > c1y) ? dy : 0.f;  f[17] = (c2y < c1y) ? dy : 0.f;
    unsigned short* o = f36 + (int64_t)li * 64;
#pragma unroll
    for (int i = 0; i < 18; ++i) {
        o[i]      = f2bf(f[i]);
        o[18 + i] = f2bf(logf(f[i] + 1e-6f));
    }
#pragma unroll
    for (int i = 36; i < 64; ++i) o[i] = 0;
}

// ---------------- encoder self-attention (T=S=128, dh=32) ----------------
__global__ __launch_bounds__(128) void enc_attn_k(
    const float* __restrict__ q, const float* __restrict__ k,
    const float* __restrict__ v, float* __restrict__ out)
{
    int b = blockIdx.x >> 3, hd = blockIdx.x & 7;
    __shared__ float kl[128][32];
    __shared__ float vl[128][32];
    int tid = threadIdx.x;
    for (int i = tid; i < 128 * 32; i += 128) {
        int s = i >> 5, j = i & 31;
        int64_t off = ((int64_t)b * N + s) * 256 + hd * 32 + j;
        kl[s][j] = k[off];
        vl[s][j] = v[off];
    }
    __syncthreads();
    int t = tid;
    int64_t qoff = ((int64_t)b * N + t) * 256 + hd * 32;
    float qr[32];
#pragma unroll
    for (int j = 0; j < 32; ++j) qr[j] = q[qoff + j] * QSCALE;
    float m = -1e30f, l = 0.f;
    for (int s = 0; s < 128; ++s) {
        float d = 0.f;
#pragma unroll
        for (int j = 0; j < 32; ++j) d += qr[j] * kl[s][j];
        float mn = fmaxf(m, d);
        l = l * __expf(m - mn) + __expf(d - mn);
        m = mn;
    }
    float acc[32] = {};
    for (int s = 0; s < 128; ++s) {
        float d = 0.f;
#pragma unroll
        for (int j = 0; j < 32; ++j) d += qr[j] * kl[s][j];
        float wgt = __expf(d - m);
#pragma unroll
        for (int j = 0; j < 32; ++j) acc[j] += wgt * vl[s][j];
    }
    float linv = 1.f / l;
#pragma unroll
    for (int j = 0; j < 32; ++j) out[qoff + j] = acc[j] * linv;
}

// ---------------- decoder cross-attention (S=64, dh=32); rpb = rows per batch ----------------
__global__ __launch_bounds__(256) void dec_attn_k(
    const float* __restrict__ q, const float* __restrict__ kp,
    const float* __restrict__ vp, float* __restrict__ out,
    int chunk0, int rows, int rpb)
{
    int hd = blockIdx.y;
    int r0 = blockIdx.x * 256;
    __shared__ float kl[2][64][32];
    __shared__ float vl[2][64][32];
    int tid = threadIdx.x;
    int b0 = (chunk0 + r0) / rpb;
    int b1 = (chunk0 + r0 + 255) / rpb;
    if (b1 >= B) b1 = B - 1;
    for (int i = tid; i < 64 * 32; i += 256) {
        int s = i >> 5, j = i & 31;
        int64_t off0 = ((int64_t)b0 * MPOSE + s) * 256 + hd * 32 + j;
        int64_t off1 = ((int64_t)b1 * MPOSE + s) * 256 + hd * 32 + j;
        kl[0][s][j] = kp[off0];
        vl[0][s][j] = vp[off0];
        kl[1][s][j] = kp[off1];
        vl[1][s][j] = vp[off1];
    }
    __syncthreads();
    int r = r0 + tid;
    if (r >= rows) return;
    int which = ((chunk0 + r) / rpb == b0) ? 0 : 1;
    int64_t qoff = (int64_t)r * 256 + hd * 32;
    float qr[32];
#pragma unroll
    for (int j = 0; j < 32; ++j) qr[j] = q[qoff + j] * QSCALE;
    float m = -1e30f, l = 0.f;
    for (int s = 0; s < 64; ++s) {
        float d = 0.f;
#pragma unroll
        for (int j = 0; j < 32; ++j) d += qr[j] * kl[which][s][j];
        float mn = fmaxf(m, d);
        l = l * __expf(m - mn) + __expf(d - mn);
        m = mn;
    }
    float acc[32] = {};
    for (int s = 0; s < 64; ++s) {
        float d = 0.f;
#pragma unroll
        for (int j = 0; j < 32; ++j) d += qr[j] * kl[which][s][j];
        float wgt = __expf(d - m);
#pragma unroll
        for (int j = 0; j < 32; ++j) acc[j] += wgt * vl[which][s][j];
    }
    float linv = 1.f / l;
#pragma unroll
    for (int j = 0; j < 32; ++j) out[qoff + j] = acc[j] * linv;
}

// ---------------- bf16 weight arena offsets (ushort units) ----------------
static constexpr int64_t WT_QKV  = 0;
static constexpr int64_t WT_EOUT = WT_QKV  + 2*196608;
static constexpr int64_t WT_EFF1 = WT_EOUT + 2*65536;
static constexpr int64_t WT_EFF2 = WT_EFF1 + 2*262144;
static constexpr int64_t WT_DQ   = WT_EFF2 + 2*262144;
static constexpr int64_t WT_DKV  = WT_DQ   + 2*65536;
static constexpr int64_t WT_DOUT = WT_DKV  + 2*131072;
static constexpr int64_t WT_DFF1 = WT_DOUT + 2*65536;
static constexpr int64_t WT_DFF2 = WT_DFF1 + 2*262144;
static constexpr int64_t WT_SW1  = WT_DFF2 + 2*262144;
static constexpr int64_t WT_SW2  = WT_SW1 + 8192;
static constexpr int64_t WT_SW3  = WT_SW2 + 32768;
static constexpr int64_t WT_BW   = WT_SW3 + 65536;
static constexpr int64_t WT_PW   = WT_BW  + 131072;
static constexpr int64_t WT_EPE  = WT_PW  + 196608;
static constexpr int64_t WT_FC1  = WT_EPE + 131072;
static constexpr int64_t WT_FC2  = WT_FC1 + 131072;
static constexpr int64_t WT_M1   = WT_FC2 + 65536;
static constexpr int64_t WT_M2   = WT_M1  + 196608;
static constexpr int64_t WT_TOTAL = WT_M2 + 98304;

// ---------------- host orchestration ----------------
extern "C" void kernel_launch(void* const* d_in, const int* in_sizes, int n_in,
                              void* d_out, int out_size, void* d_ws, size_t ws_size,
                              hipStream_t stream)
{
    (void)in_sizes; (void)n_in; (void)out_size;
    const float* boxes     = (const float*)d_in[0];
    const float* embeds    = (const float*)d_in[1];
    const float* sizes     = (const float*)d_in[2];
    const float* pose      = (const float*)d_in[3];
    const float* line      = (const float*)d_in[4];
    const float* sw1 = (const float*)d_in[5];  const float* sb1 = (const float*)d_in[6];
    const float* sw2 = (const float*)d_in[7];  const float* sb2 = (const float*)d_in[8];
    const float* sw3 = (const float*)d_in[9];  const float* sb3 = (const float*)d_in[10];
    const float* bw  = (const float*)d_in[11]; const float* bb  = (const float*)d_in[12];
    const float* pw  = (const float*)d_in[13]; const float* pb  = (const float*)d_in[14];
    const float* lw  = (const float*)d_in[15]; const float* lb  = (const float*)d_in[16];
    const float* enc_pe_w  = (const float*)d_in[17]; const float* enc_pe_b = (const float*)d_in[18];
    const float* enc_qkv_w = (const float*)d_in[19]; const float* enc_qkv_b = (const float*)d_in[20];
    const float* enc_out_w = (const float*)d_in[21]; const float* enc_out_b = (const float*)d_in[22];
    const float* enc_ff1_w = (const float*)d_in[23]; const float* enc_ff1_b = (const float*)d_in[24];
    const float* enc_ff2_w = (const float*)d_in[25]; const float* enc_ff2_b = (const float*)d_in[26];
    const float* enc_ln1_g = (const float*)d_in[27]; const float* enc_ln1_b = (const float*)d_in[28];
    const float* enc_ln2_g = (const float*)d_in[29]; const float* enc_ln2_b = (const float*)d_in[30];
    const float* dec_q_w   = (const float*)d_in[31]; const float* dec_q_b  = (const float*)d_in[32];
    const float* dec_kv_w  = (const float*)d_in[33]; const float* dec_kv_b = (const float*)d_in[34];
    const float* dec_out_w = (const float*)d_in[35]; const float* dec_out_b = (const float*)d_in[36];
    const float* dec_ff1_w = (const float*)d_in[37]; const float* dec_ff1_b = (const float*)d_in[38];
    const float* dec_ff2_w = (const float*)d_in[39]; const float* dec_ff2_b = (const float*)d_in[40];
    const float* dec_ln1_g = (const float*)d_in[41]; const float* dec_ln1_b = (const float*)d_in[42];
    const float* dec_ln2_g = (const float*)d_in[43]; const float* dec_ln2_b = (const float*)d_in[44];
    const float* fc1_w = (const float*)d_in[45]; const float* fc1_b = (const float*)d_in[46];
    const float* fc2_w = (const float*)d_in[47]; const float* fc2_b = (const float*)d_in[48];
    const float* mln1_g = (const float*)d_in[49]; const float* mln1_b = (const float*)d_in[50];
    const float* mln2_g = (const float*)d_in[51]; const float* mln2_b = (const float*)d_in[52];
    const float* m1_w = (const float*)d_in[53]; const float* m1_b = (const float*)d_in[54];
    const float* m2_w = (const float*)d_in[55]; const float* m2_b = (const float*)d_in[56];
    float* out = (float*)d_out;

    // ---- workspace layout ----
    float* base = (float*)d_ws;
    int64_t wsf = (int64_t)(ws_size / sizeof(float));
    float* x_   = base;                       // 524288 (tokens)
    float* bpw_ = x_   + 524288;              // 524288 (pe_tok)
    float* lf   = bpw_ + 524288;              // 4096
    float* kv0  = lf   + 4096;                // 4 x 262144 (dec K/V; later U,V)
    unsigned short* wt = (unsigned short*)(kv0 + 4 * 262144);
    float* arena = (float*)(wt + WT_TOTAL);
    const int64_t LIVE_F = arena - base;
    int64_t arena_f = wsf - LIVE_F;
    if (arena_f < 0) arena_f = 0;

    // setup-phase views into arena
    float* posx  = arena;                     // 524288
    float* boxpe = posx  + 524288;            // 1048576
    float* e_q   = boxpe + 1048576;
    float* e_k   = e_q   + 524288;
    float* e_v   = e_k   + 524288;
    float* e_t   = e_v   + 524288;
    float* e_ff  = e_t   + 524288;            // 2097152
    float* pctx  = e_ff  + 2097152;           // 262144
    float* lm    = pctx  + 262144;            // 32768

    // pair-chunk (bf16 buffers): per-row ushorts = z 512 + z2 384 + t1 64 + t2 128 + t3 256 + t4 256 = 1600 (= 800 floats)
    int64_t rc = ((arena_f * 4) / 3200) & ~127LL;
    if (rc > BP) rc = BP;
    if (rc < 128) rc = 128;

    // ---- stage 0: weight prep ----
    for (int i = 0; i < 2; ++i) {
        wprep(stream, enc_qkv_w + (int64_t)i*196608, 256, 768,  wt + WT_QKV  + i*196608, 256);
        wprep(stream, enc_out_w + (int64_t)i*65536,  256, 256,  wt + WT_EOUT + i*65536,  256);
        wprep(stream, enc_ff1_w + (int64_t)i*262144, 256, 1024, wt + WT_EFF1 + i*262144, 256);
        wprep(stream, enc_ff2_w + (int64_t)i*262144, 1024, 256, wt + WT_EFF2 + i*262144, 1024);
        wprep(stream, dec_q_w   + (int64_t)i*65536,  256, 256,  wt + WT_DQ   + i*65536,  256);
        wprep(stream, dec_kv_w  + (int64_t)i*131072, 256, 512,  wt + WT_DKV  + i*131072, 256);
        wprep(stream, dec_out_w + (int64_t)i*65536,  256, 256,  wt + WT_DOUT + i*65536,  256);
        wprep(stream, dec_ff1_w + (int64_t)i*262144, 256, 1024, wt + WT_DFF1 + i*262144, 256);
        wprep(stream, dec_ff2_w + (int64_t)i*262144, 1024, 256, wt + WT_DFF2 + i*262144, 1024);
    }
    wprep(stream, sw1, 36, 128,  wt + WT_SW1, 64);
    wprep(stream, sw2, 128, 256, wt + WT_SW2, 128);
    wprep(stream, sw3, 256, 256, wt + WT_SW3, 256);
    wprep(stream, bw,  512, 256, wt + WT_BW,  512);
    wprep(stream, pw,  768, 256, wt + WT_PW,  768);
    wprep(stream, enc_pe_w, 512, 256, wt + WT_EPE, 512);
    wprep(stream, fc1_w, 512, 256, wt + WT_FC1, 512);
    wprep(stream, fc2_w, 256, 256, wt + WT_FC2, 256);
    wprep(stream, m1_w, 512, 384, wt + WT_M1, 512);
    wprep(stream, m2_w, 384, 256, wt + WT_M2, 384);

    // ---- stage A: small precomputes ----
    line_mean_k<<<8192, 256, 0, stream>>>(line, lm);
    line_proj_k<<<dim3(8, B), 256, 0, stream>>>(lm, lw, lb, lf);
    boxpe_k<<<(int)BN, 512, 0, stream>>>(boxes, sizes, boxpe);
    bgemm(stream, boxpe, nullptr, 512, wt + WT_EPE, 512, enc_pe_b, posx, 256, (int)BN, 256, 512, false, false, false);
    bgemm(stream, boxpe, nullptr, 512, wt + WT_BW,  512, bb,       bpw_, 256, (int)BN, 256, 512, false, false, false);
    bgemm(stream, pose,  nullptr, 768, wt + WT_PW,  768, pb,       pctx, 256, B*MPOSE, 256, 768, false, false, false);
    for (int l = 0; l < 2; ++l) {
        const float* bkv = dec_kv_b + (int64_t)l * 512;
        bgemm(stream, pctx, nullptr, 256, wt + WT_DKV + l*131072,         256, bkv,       kv0 + (2*l+0)*262144, 256, B*MPOSE, 256, 256, false, false, false);
        bgemm(stream, pctx, nullptr, 256, wt + WT_DKV + l*131072 + 65536, 256, bkv + 256, kv0 + (2*l+1)*262144, 256, B*MPOSE, 256, 256, false, false, false);
    }

    // ---- stage B: encoder (2 layers) on x_ (2048 tokens) ----
    hipMemcpyAsync(x_, embeds, BN * 256 * sizeof(float), hipMemcpyDeviceToDevice, stream);
    for (int i = 0; i < 2; ++i) {
        const unsigned short* Wq = wt + WT_QKV + (int64_t)i * 196608;
        const float* bqkv = enc_qkv_b + (int64_t)i * 768;
        bgemm(stream, x_, posx, 256, Wq,          256, bqkv,       e_q, 256, (int)BN, 256, 256, false, false, false);
        bgemm(stream, x_, posx, 256, Wq + 65536,  256, bqkv + 256, e_k, 256, (int)BN, 256, 256, false, false, false);
        bgemm(stream, x_, nullptr, 256, Wq + 131072, 256, bqkv + 512, e_v, 256, (int)BN, 256, 256, false, false, false);
        enc_attn_k<<<B * 8, 128, 0, stream>>>(e_q, e_k, e_v, e_t);
        bgemm(stream, e_t, nullptr, 256, wt + WT_EOUT + (int64_t)i*65536, 256, enc_out_b + i * 256,
              e_q, 256, (int)BN, 256, 256, false, false, false);
        ln_k<<<(int)(BN / 4), 256, 0, stream>>>(x_, x_, e_q, enc_ln1_g + i * 256, enc_ln1_b + i * 256, (int)BN);
        bgemm(stream, x_, nullptr, 256, wt + WT_EFF1 + (int64_t)i*262144, 256, enc_ff1_b + i * 1024,
              e_ff, 1024, (int)BN, 1024, 256, true, false, false);
        bgemm(stream, e_ff, nullptr, 1024, wt + WT_EFF2 + (int64_t)i*262144, 1024, enc_ff2_b + i * 256,
              e_t, 256, (int)BN, 256, 1024, false, false, false);
        ln_k<<<(int)(BN / 4), 256, 0, stream>>>(x_, x_, e_t, enc_ln2_g + i * 256, enc_ln2_b + i * 256, (int)BN);
    }

    // ---- stage C: decoder on tokens (h/o streams collapse) ----
    add_lf_k<<<(int)BN, 256, 0, stream>>>(bpw_, lf);
    for (int l = 0; l < 2; ++l) {
        const float* kp = kv0 + (2*l+0)*262144;
        const float* vp = kv0 + (2*l+1)*262144;
        bgemm(stream, x_, bpw_, 256, wt + WT_DQ + (int64_t)l*65536, 256, dec_q_b + l * 256,
              e_q, 256, (int)BN, 256, 256, false, false, false);
        dec_attn_k<<<dim3((int)(BN / 256), 8), 256, 0, stream>>>(e_q, kp, vp, e_t, 0, (int)BN, N);
        bgemm(stream, e_t, nullptr, 256, wt + WT_DOUT + (int64_t)l*65536, 256, dec_out_b + l * 256,
              e_q, 256, (int)BN, 256, 256, false, false, false);
        ln_k<<<(int)(BN / 4), 256, 0, stream>>>(x_, x_, e_q, dec_ln1_g + l * 256, dec_ln1_b + l * 256, (int)BN);
        bgemm(stream, x_, nullptr, 256, wt + WT_DFF1 + (int64_t)l*262144, 256, dec_ff1_b + l * 1024,
              e_ff, 1024, (int)BN, 1024, 256, true, false, false);
        bgemm(stream, e_ff, nullptr, 1024, wt + WT_DFF2 + (int64_t)l*262144, 1024, dec_ff2_b + l * 256,
              e_t, 256, (int)BN, 256, 1024, false, false, false);
        ln_k<<<(int)(BN / 4), 256, 0, stream>>>(x_, x_, e_t, dec_ln2_g + l * 256, dec_ln2_b + l * 256, (int)BN);
    }
    // U = y@fc1_top + fc1_b, V = y@fc1_bot
    float* U = kv0;
    float* V = kv0 + 524288;
    bgemm(stream, x_, nullptr, 256, wt + WT_FC1,       512, fc1_b,   U, 256, (int)BN, 256, 256, false, false, false);
    bgemm(stream, x_, nullptr, 256, wt + WT_FC1 + 256, 512, nullptr, V, 256, (int)BN, 256, 256, false, false, false);

    // ---- stage D: per-pair head, chunked, all-bf16 intermediates ----
    for (int64_t c0 = 0; c0 < BP; c0 += rc) {
        int rows = (int)((BP - c0 < rc) ? (BP - c0) : rc);   // multiple of 128
        unsigned short* zb = (unsigned short*)arena;         // rc x 512 (hoLn | spLn)
        unsigned short* z2 = zb + (int64_t)rc * 512;         // rc x 384
        unsigned short* t1 = z2 + (int64_t)rc * 384;         // rc x 64 (f36)
        unsigned short* t2 = t1 + (int64_t)rc * 64;          // rc x 128
        unsigned short* t3 = t2 + (int64_t)rc * 128;         // rc x 256
        unsigned short* t4 = t3 + (int64_t)rc * 256;         // rc x 256

        // spatial MLP (bf16 chain)
        f36_k<<<(rows + 255) / 256, 256, 0, stream>>>(boxes, sizes, t1, (int)c0, rows);
        hgemm(stream, t1, 64,  wt + WT_SW1, 64,  sb1, t2, 128, rows, 128, 36,  true, false, true);
        hgemm(stream, t2, 128, wt + WT_SW2, 128, sb2, t3, 256, rows, 256, 128, true, false, true);
        hgemm(stream, t3, 256, wt + WT_SW3, 256, sb3, t4, 256, rows, 256, 256, true, false, true);
        hgemm(stream, t4, 256, wt + WT_FC2, 256, fc2_b, t3, 256, rows, 256, 256, false, false, true);
        lnh_k<<<rows / 4, 256, 0, stream>>>(zb + 256, 512, t3, 256, mln2_g, mln2_b, rows);   // spLn
        // hoLn = LN(U[b,i] + V[b,j]) -> z[:,0:256]
        pairln_k<<<rows / 4, 256, 0, stream>>>(U, V, mln1_g, mln1_b, zb, 512, (int)c0, rows);
        // z2 = relu(relu(z) @ m1 + m1_b)   (single K=512 GEMM)
        hgemm(stream, zb, 512, wt + WT_M1, 512, m1_b, z2, 384, rows, 384, 512, true, true, true);
        // out = relu(z2 @ m2 + m2_b)
        hgemm(stream, z2, 384, wt + WT_M2, 384, m2_b, out + c0 * 256, 256, rows, 256, 384, true, false, false);
    }
}

// Round 6
// 889.640 us; speedup vs baseline: 15.7045x; 1.1588x over previous
//
#include <hip/hip_runtime.h>
#include <stdint.h>

// ---------------- problem dims ----------------
static constexpr int B      = 16;
static constexpr int N      = 128;
static constexpr int P      = 4064;     // 32*(128-1)
static constexpr int MPOSE  = 64;
static constexpr int64_t BN = (int64_t)B * N;   // 2048
static constexpr int64_t BP = (int64_t)B * P;   // 65024 = 508*128

#define TWO_PI 6.283185307179586f
#define QSCALE 0.17677669529663687f  /* 1/sqrt(32) */

typedef __attribute__((ext_vector_type(4))) float f32x4;
typedef __attribute__((ext_vector_type(8))) short bf16x8;
typedef __attribute__((ext_vector_type(8))) unsigned short u16x8;
typedef __attribute__((ext_vector_type(4))) unsigned short u16x4;

__device__ __forceinline__ unsigned short f2bf(float f) {
    union { float f; unsigned u; } v; v.f = f;
    unsigned r = (v.u + 0x7fffu + ((v.u >> 16) & 1u)) >> 16;   // RNE
    return (unsigned short)r;
}
__device__ __forceinline__ float bf2f(unsigned short u) {
    union { unsigned u; float f; } v; v.u = (unsigned)u << 16;
    return v.f;
}
__device__ __forceinline__ void pair_xy(int p, int& x, int& y) {
    x = p / 127;
    int r = p - x * 127;
    y = (r < x) ? r : r + 1;
}

// ---------------- batched weight prep: W[K][N] fp32 -> Wt[N][Kpad] bf16 ----------------
struct WDesc { const float* src; int64_t dstOff; int K, Nn, Kpad, blockStart; };
struct WTable { WDesc d[29]; int nDesc; };

__global__ __launch_bounds__(256) void wprep_all_k(WTable t, unsigned short* __restrict__ wt)
{
    __shared__ float s[32][33];
    int bid = blockIdx.x;
    int di = 0;
    for (int i = 1; i < t.nDesc; ++i) if (t.d[i].blockStart <= bid) di = i;
    const WDesc& d = t.d[di];
    int lbid = bid - d.blockStart;
    int kTiles = d.Kpad >> 5;
    int k0 = (lbid % kTiles) * 32, n0 = (lbid / kTiles) * 32;
    int tx = threadIdx.x & 31, ty = threadIdx.x >> 5;
#pragma unroll
    for (int i = 0; i < 4; ++i) {
        int k = k0 + ty + i * 8;
        s[ty + i * 8][tx] = (k < d.K) ? d.src[(int64_t)k * d.Nn + n0 + tx] : 0.f;
    }
    __syncthreads();
    unsigned short* dst = wt + d.dstOff;
#pragma unroll
    for (int i = 0; i < 4; ++i) {
        int n = n0 + ty + i * 8;
        dst[(int64_t)n * d.Kpad + k0 + tx] = f2bf(s[tx][ty + i * 8]);
    }
}

// ---------------- fp32-A bf16 MFMA GEMM (token stages) ----------------
template <bool RELU_OUT, bool RELU_A>
__global__ __launch_bounds__(256) void bgemm_k(
    const float* __restrict__ A, const float* __restrict__ A2, int lda,
    const unsigned short* __restrict__ Bt, int ldk,
    const float* __restrict__ bias,
    float* __restrict__ C, int ldc,
    int K, int kSteps)
{
    __shared__ unsigned short As[128][40];
    __shared__ unsigned short Bs[128][40];
    const int tid  = threadIdx.x;
    const int lane = tid & 63;
    const int wave = tid >> 6;
    const int wr = wave >> 1, wc = wave & 1;
    const int row0 = blockIdx.y * 128, col0 = blockIdx.x * 128;
    const int l15 = lane & 15, l4 = lane >> 4;
    const int sr = tid >> 1;
    const int sh = (tid & 1) * 16;

    f32x4 acc[4][4] = {};

    for (int ks = 0; ks < kSteps; ++ks) {
        const int k0 = ks * 32;
        {
            const int64_t off = (int64_t)(row0 + sr) * lda + k0 + sh;
            const float* ap = A + off;
            float v[16];
#pragma unroll
            for (int i = 0; i < 4; ++i) {
                float4 tv = ((const float4*)ap)[i];
                v[i*4+0] = tv.x; v[i*4+1] = tv.y; v[i*4+2] = tv.z; v[i*4+3] = tv.w;
            }
            if (A2) {
                const float* ap2 = A2 + off;
#pragma unroll
                for (int i = 0; i < 4; ++i) {
                    float4 tv = ((const float4*)ap2)[i];
                    v[i*4+0] += tv.x; v[i*4+1] += tv.y; v[i*4+2] += tv.z; v[i*4+3] += tv.w;
                }
            }
            if (RELU_A) {
#pragma unroll
                for (int j = 0; j < 16; ++j) v[j] = fmaxf(v[j], 0.f);
            }
            u16x8 p0, p1;
#pragma unroll
            for (int j = 0; j < 8; ++j) { p0[j] = f2bf(v[j]); p1[j] = f2bf(v[8 + j]); }
            *(u16x8*)&As[sr][sh]     = p0;
            *(u16x8*)&As[sr][sh + 8] = p1;
        }
        {
            const unsigned short* bp = Bt + (int64_t)(col0 + sr) * ldk + k0 + sh;
            u16x8 q0 = *(const u16x8*)bp;
            u16x8 q1 = *(const u16x8*)(bp + 8);
            *(u16x8*)&Bs[sr][sh]     = q0;
            *(u16x8*)&Bs[sr][sh + 8] = q1;
        }
        __syncthreads();
        bf16x8 af[4], bfr[4];
#pragma unroll
        for (int f = 0; f < 4; ++f) {
            af[f]  = *(const bf16x8*)&As[wr * 64 + f * 16 + l15][l4 * 8];
            bfr[f] = *(const bf16x8*)&Bs[wc * 64 + f * 16 + l15][l4 * 8];
        }
#pragma unroll
        for (int i = 0; i < 4; ++i)
#pragma unroll
            for (int j = 0; j < 4; ++j)
                acc[i][j] = __builtin_amdgcn_mfma_f32_16x16x32_bf16(af[i], bfr[j], acc[i][j], 0, 0, 0);
        __syncthreads();
    }
#pragma unroll
    for (int i = 0; i < 4; ++i) {
        int rb = row0 + wr * 64 + i * 16 + l4 * 4;
#pragma unroll
        for (int j = 0; j < 4; ++j) {
            int c = col0 + wc * 64 + j * 16 + l15;
            float bv = bias ? bias[c] : 0.f;
#pragma unroll
            for (int e = 0; e < 4; ++e) {
                float vv = acc[i][j][e] + bv;
                if (RELU_OUT) vv = fmaxf(vv, 0.f);
                C[(int64_t)(rb + e) * ldc + c] = vv;
            }
        }
    }
}

static void bgemm(hipStream_t st,
                  const float* A, const float* A2, int lda,
                  const unsigned short* Bt, int ldk, const float* bias,
                  float* C, int ldc, int M, int Ncols, int K,
                  bool reluOut, bool reluA)
{
    int kSteps = K / 32;
    dim3 g(Ncols / 128, M / 128), b(256);
    if (!reluOut && !reluA)      bgemm_k<false,false><<<g,b,0,st>>>(A,A2,lda,Bt,ldk,bias,C,ldc,K,kSteps);
    else if (reluOut && !reluA)  bgemm_k<true,false><<<g,b,0,st>>>(A,A2,lda,Bt,ldk,bias,C,ldc,K,kSteps);
    else if (!reluOut && reluA)  bgemm_k<false,true><<<g,b,0,st>>>(A,A2,lda,Bt,ldk,bias,C,ldc,K,kSteps);
    else                         bgemm_k<true,true><<<g,b,0,st>>>(A,A2,lda,Bt,ldk,bias,C,ldc,K,kSteps);
}

// ---------------- fused two-stage GEMM (pair stages) ----------------
// C = act2( act1(reluA?relu(A):A @ W1 + b1) @ W2 + b2 ), N2 = 256 fixed.
// A bf16 [M][lda]; W1 [n1tiles*128][ldk1]; W2 [256][ldk2 = n1tiles*128].
// Block-K accumulation: per stage-1 col tile j, D1 tile -> LDS, then partial stage-2.
template <bool RELU_A, bool RELU2, bool OUT_BF16>
__global__ __launch_bounds__(256) void fgemm_k(
    const unsigned short* __restrict__ A, int lda,
    const unsigned short* __restrict__ W1, int ldk1, const float* __restrict__ b1,
    const unsigned short* __restrict__ W2, int ldk2, const float* __restrict__ b2,
    void* __restrict__ Cv, int ldc,
    int ksteps1, int n1tiles)
{
    __shared__ unsigned short As[128][40];
    __shared__ unsigned short Bs[128][40];
    __shared__ unsigned short D1s[128][136];
    const int tid  = threadIdx.x;
    const int lane = tid & 63;
    const int wave = tid >> 6;
    const int wr = wave >> 1, wc = wave & 1;
    const int row0 = blockIdx.x * 128;
    const int l15 = lane & 15, l4 = lane >> 4;
    const int sr = tid >> 1;
    const int sh = (tid & 1) * 16;

    f32x4 acc2[2][4][4] = {};

    for (int j = 0; j < n1tiles; ++j) {
        f32x4 acc1[4][4] = {};
        for (int ks = 0; ks < ksteps1; ++ks) {
            const int k0 = ks * 32;
            {
                const unsigned short* ap = A + (int64_t)(row0 + sr) * lda + k0 + sh;
                u16x8 q0 = *(const u16x8*)ap;
                u16x8 q1 = *(const u16x8*)(ap + 8);
                if (RELU_A) {
#pragma unroll
                    for (int q = 0; q < 8; ++q) {
                        q0[q] = (q0[q] & 0x8000u) ? 0 : q0[q];
                        q1[q] = (q1[q] & 0x8000u) ? 0 : q1[q];
                    }
                }
                *(u16x8*)&As[sr][sh]     = q0;
                *(u16x8*)&As[sr][sh + 8] = q1;
            }
            {
                const unsigned short* bp = W1 + (int64_t)(j * 128 + sr) * ldk1 + k0 + sh;
                *(u16x8*)&Bs[sr][sh]     = *(const u16x8*)bp;
                *(u16x8*)&Bs[sr][sh + 8] = *(const u16x8*)(bp + 8);
            }
            __syncthreads();
            bf16x8 af[4], bfr[4];
#pragma unroll
            for (int f = 0; f < 4; ++f) {
                af[f]  = *(const bf16x8*)&As[wr * 64 + f * 16 + l15][l4 * 8];
                bfr[f] = *(const bf16x8*)&Bs[wc * 64 + f * 16 + l15][l4 * 8];
            }
#pragma unroll
            for (int i = 0; i < 4; ++i)
#pragma unroll
                for (int jj = 0; jj < 4; ++jj)
                    acc1[i][jj] = __builtin_amdgcn_mfma_f32_16x16x32_bf16(af[i], bfr[jj], acc1[i][jj], 0, 0, 0);
            __syncthreads();
        }
        // D1 tile epilogue -> LDS (bf16, relu always for stage 1)
#pragma unroll
        for (int i = 0; i < 4; ++i) {
            int rb = wr * 64 + i * 16 + l4 * 4;
#pragma unroll
            for (int jj = 0; jj < 4; ++jj) {
                int c = wc * 64 + jj * 16 + l15;
                float bv = b1[j * 128 + c];
#pragma unroll
                for (int e = 0; e < 4; ++e) {
                    float vv = fmaxf(acc1[i][jj][e] + bv, 0.f);
                    D1s[rb + e][c] = f2bf(vv);
                }
            }
        }
        __syncthreads();
        // stage-2 partial: K-chunk = this 128-wide D1 tile
#pragma unroll
        for (int n = 0; n < 2; ++n) {
            for (int kk = 0; kk < 4; ++kk) {
                {
                    const unsigned short* bp = W2 + (int64_t)(n * 128 + sr) * ldk2 + j * 128 + kk * 32 + sh;
                    *(u16x8*)&Bs[sr][sh]     = *(const u16x8*)bp;
                    *(u16x8*)&Bs[sr][sh + 8] = *(const u16x8*)(bp + 8);
                }
                __syncthreads();
                bf16x8 af[4], bfr[4];
#pragma unroll
                for (int f = 0; f < 4; ++f) {
                    af[f]  = *(const bf16x8*)&D1s[wr * 64 + f * 16 + l15][kk * 32 + l4 * 8];
                    bfr[f] = *(const bf16x8*)&Bs[wc * 64 + f * 16 + l15][l4 * 8];
                }
#pragma unroll
                for (int i = 0; i < 4; ++i)
#pragma unroll
                    for (int jj = 0; jj < 4; ++jj)
                        acc2[n][i][jj] = __builtin_amdgcn_mfma_f32_16x16x32_bf16(af[i], bfr[jj], acc2[n][i][jj], 0, 0, 0);
                __syncthreads();
            }
        }
    }
    // final epilogue
#pragma unroll
    for (int n = 0; n < 2; ++n)
#pragma unroll
    for (int i = 0; i < 4; ++i) {
        int rb = row0 + wr * 64 + i * 16 + l4 * 4;
#pragma unroll
        for (int jj = 0; jj < 4; ++jj) {
            int c = n * 128 + wc * 64 + jj * 16 + l15;
            float bv = b2[c];
#pragma unroll
            for (int e = 0; e < 4; ++e) {
                float vv = acc2[n][i][jj][e] + bv;
                if (RELU2) vv = fmaxf(vv, 0.f);
                int64_t off = (int64_t)(rb + e) * ldc + c;
                if (OUT_BF16) ((unsigned short*)Cv)[off] = f2bf(vv);
                else          ((float*)Cv)[off] = vv;
            }
        }
    }
}

// ---------------- LayerNorm fp32 (D=256), optional residual ----------------
__global__ __launch_bounds__(256) void ln_k(
    float* __restrict__ out, const float* __restrict__ x, const float* __restrict__ res,
    const float* __restrict__ g, const float* __restrict__ be, int rows)
{
    int wave = threadIdx.x >> 6, lane = threadIdx.x & 63;
    int row = blockIdx.x * 4 + wave;
    if (row >= rows) return;
    int64_t base = (int64_t)row * 256 + lane * 4;
    float4 v = *(const float4*)(x + base);
    if (res) {
        float4 r = *(const float4*)(res + base);
        v.x += r.x; v.y += r.y; v.z += r.z; v.w += r.w;
    }
    float s  = v.x + v.y + v.z + v.w;
    float sq = v.x*v.x + v.y*v.y + v.z*v.z + v.w*v.w;
#pragma unroll
    for (int off = 1; off < 64; off <<= 1) {
        s  += __shfl_xor(s, off);
        sq += __shfl_xor(sq, off);
    }
    float m = s * (1.f/256.f);
    float var = sq * (1.f/256.f) - m * m;
    float inv = rsqrtf(var + 1e-5f);
    int c = lane * 4;
    float4 gg = *(const float4*)(g + c);
    float4 bb = *(const float4*)(be + c);
    float4 o;
    o.x = (v.x - m) * inv * gg.x + bb.x;
    o.y = (v.y - m) * inv * gg.y + bb.y;
    o.z = (v.z - m) * inv * gg.z + bb.z;
    o.w = (v.w - m) * inv * gg.w + bb.w;
    *(float4*)(out + base) = o;
}

// ---------------- LayerNorm bf16 -> bf16 at stride ldo ----------------
__global__ __launch_bounds__(256) void lnh_k(
    unsigned short* __restrict__ outp, int ldo,
    const unsigned short* __restrict__ x, int ldx,
    const float* __restrict__ g, const float* __restrict__ be, int rows)
{
    int wave = threadIdx.x >> 6, lane = threadIdx.x & 63;
    int row = blockIdx.x * 4 + wave;
    if (row >= rows) return;
    u16x4 u = *(const u16x4*)(x + (int64_t)row * ldx + lane * 4);
    float4 v;
    v.x = bf2f(u[0]); v.y = bf2f(u[1]); v.z = bf2f(u[2]); v.w = bf2f(u[3]);
    float s  = v.x + v.y + v.z + v.w;
    float sq = v.x*v.x + v.y*v.y + v.z*v.z + v.w*v.w;
#pragma unroll
    for (int off = 1; off < 64; off <<= 1) {
        s  += __shfl_xor(s, off);
        sq += __shfl_xor(sq, off);
    }
    float m = s * (1.f/256.f);
    float var = sq * (1.f/256.f) - m * m;
    float inv = rsqrtf(var + 1e-5f);
    int c = lane * 4;
    float4 gg = *(const float4*)(g + c);
    float4 bb = *(const float4*)(be + c);
    u16x4 o;
    o[0] = f2bf((v.x - m) * inv * gg.x + bb.x);
    o[1] = f2bf((v.y - m) * inv * gg.y + bb.y);
    o[2] = f2bf((v.z - m) * inv * gg.z + bb.z);
    o[3] = f2bf((v.w - m) * inv * gg.w + bb.w);
    *(u16x4*)(outp + (int64_t)row * ldo + c) = o;
}

// ---------------- pair-gather + LN: LN(U[b,i] + V[b,j] + fc1_b) -> bf16 ----------------
__global__ __launch_bounds__(256) void pairln_k(
    const float* __restrict__ UV,     // [2048][512]: U | V
    const float* __restrict__ fb,
    const float* __restrict__ g, const float* __restrict__ be,
    unsigned short* __restrict__ outp, int ldo, int chunk0, int rows)
{
    int wave = threadIdx.x >> 6, lane = threadIdx.x & 63;
    int li = blockIdx.x * 4 + wave;
    if (li >= rows) return;
    int gp = chunk0 + li;
    int b = gp / P, p = gp - b * P;
    int xi, yi; pair_xy(p, xi, yi);
    int c = lane * 4;
    float4 u  = *(const float4*)(UV + ((int64_t)(b * 128 + xi)) * 512 + c);
    float4 vv = *(const float4*)(UV + ((int64_t)(b * 128 + yi)) * 512 + 256 + c);
    float4 fbv = *(const float4*)(fb + c);
    float4 v;
    v.x = u.x + vv.x + fbv.x; v.y = u.y + vv.y + fbv.y;
    v.z = u.z + vv.z + fbv.z; v.w = u.w + vv.w + fbv.w;
    float s  = v.x + v.y + v.z + v.w;
    float sq = v.x*v.x + v.y*v.y + v.z*v.z + v.w*v.w;
#pragma unroll
    for (int off = 1; off < 64; off <<= 1) {
        s  += __shfl_xor(s, off);
        sq += __shfl_xor(sq, off);
    }
    float m = s * (1.f/256.f);
    float var = sq * (1.f/256.f) - m * m;
    float inv = rsqrtf(var + 1e-5f);
    float4 gg = *(const float4*)(g + c);
    float4 bb = *(const float4*)(be + c);
    u16x4 o;
    o[0] = f2bf((v.x - m) * inv * gg.x + bb.x);
    o[1] = f2bf((v.y - m) * inv * gg.y + bb.y);
    o[2] = f2bf((v.z - m) * inv * gg.z + bb.z);
    o[3] = f2bf((v.w - m) * inv * gg.w + bb.w);
    *(u16x4*)(outp + (int64_t)li * ldo + c) = o;
}

// ---------------- line: mean over 8x8, then proj ----------------
__global__ __launch_bounds__(256) void line_mean_k(const float* __restrict__ line, float* __restrict__ lm)
{
    int wave = threadIdx.x >> 6, lane = threadIdx.x & 63;
    int bc = blockIdx.x * 4 + wave;
    float v = line[(int64_t)bc * 64 + lane];
#pragma unroll
    for (int off = 1; off < 64; off <<= 1) v += __shfl_xor(v, off);
    if (lane == 0) lm[bc] = v * (1.f/64.f);
}

__global__ __launch_bounds__(256) void line_proj_k(
    const float* __restrict__ lm, const float* __restrict__ lw,
    const float* __restrict__ lb, float* __restrict__ lf)
{
    __shared__ float red[8][32];
    int b = blockIdx.y, jg = blockIdx.x;
    int jj = threadIdx.x & 31, cc = threadIdx.x >> 5;
    int j = jg * 32 + jj;
    const float* lmb = lm + (int64_t)b * 2048 + cc * 256;
    const float* lwp = lw + (int64_t)(cc * 256) * 256 + j;
    float acc = 0.f;
#pragma unroll 4
    for (int k = 0; k < 256; ++k) acc += lmb[k] * lwp[(int64_t)k * 256];
    red[cc][jj] = acc;
    __syncthreads();
    if (cc == 0) {
        float s = lb[j];
#pragma unroll
        for (int i = 0; i < 8; ++i) s += red[i][jj];
        lf[b * 256 + j] = s;
    }
}

// ---------------- add line-feat broadcast ----------------
__global__ __launch_bounds__(256) void add_lf_k(float* __restrict__ bpw, const float* __restrict__ lf)
{
    int r = blockIdx.x, c = threadIdx.x;
    bpw[(int64_t)r * 256 + c] += lf[(r >> 7) * 256 + c];
}

// ---------------- sinusoidal box PE ----------------
__global__ __launch_bounds__(512) void boxpe_k(
    const float* __restrict__ boxes, const float* __restrict__ sizes, float* __restrict__ boxpe)
{
    int row = blockIdx.x;
    int b = row >> 7;
    int i = threadIdx.x;
    const float* bx = boxes + (int64_t)row * 4;
    float h = sizes[b * 2 + 0], w = sizes[b * 2 + 1];
    float x0 = bx[0] / w, y0 = bx[1] / h, x1 = bx[2] / w, y1 = bx[3] / h;
    int seg = i >> 7, j = i & 127, k = j >> 1;
    float val;
    switch (seg) {
        case 0: val = (y0 + y1) * 0.5f; break;
        case 1: val = (x0 + x1) * 0.5f; break;
        case 2: val = (y1 - y0); break;
        default: val = (x1 - x0); break;
    }
    float dimt = exp2f((float)k * (4.321928094887362f / 64.f));   // 20^(k/64)
    float arg = val * TWO_PI / dimt;
    boxpe[(int64_t)row * 512 + i] = (j & 1) ? cosf(arg) : sinf(arg);
}

// ---------------- spatial 36 features -> bf16, rows padded to 64 ----------------
__global__ __launch_bounds__(256) void f36_k(
    const float* __restrict__ boxes, const float* __restrict__ sizes,
    unsigned short* __restrict__ f36, int chunk0, int cnt)
{
    int li = blockIdx.x * 256 + threadIdx.x;
    if (li >= cnt) return;
    int gp = chunk0 + li;
    int b = gp / P, p = gp - b * P;
    int xi, yi; pair_xy(p, xi, yi);
    const float* b1 = boxes + ((int64_t)b * N + xi) * 4;
    const float* b2 = boxes + ((int64_t)b * N + yi) * 4;
    float h = sizes[b * 2 + 0], w = sizes[b * 2 + 1];
    float c1x = (b1[0] + b1[2]) * 0.5f, c1y = (b1[1] + b1[3]) * 0.5f;
    float c2x = (b2[0] + b2[2]) * 0.5f, c2y = (b2[1] + b2[3]) * 0.5f;
    float w1 = b1[2] - b1[0], h1 = b1[3] - b1[1];
    float w2 = b2[2] - b2[0], h2 = b2[3] - b2[1];
    float a1 = w1 * h1, a2 = w2 * h2;
    float dx = fabsf(c2x - c1x) / (w1 + 1e-6f);
    float dy = fabsf(c2y - c1y) / (h1 + 1e-6f);
    float ix = fmaxf(fminf(b1[2], b2[2]) - fmaxf(b1[0], b2[0]), 0.f);
    float iy = fmaxf(fminf(b1[3], b2[3]) - fmaxf(b1[1], b2[1]), 0.f);
    float inter = ix * iy;
    float iou = inter / (a1 + a2 - inter + 1e-6f);
    float f[18];
    f[0] = c1x / w;  f[1] = c1y / h;  f[2] = c2x / w;  f[3] = c2y / h;
    f[4] = w1 / w;   f[5] = h1 / h;   f[6] = w2 / w;   f[7] = h2 / h;
    f[8] = a1 / (h * w); f[9] = a2 / (h * w); f[10] = a2 / (a1 + 1e-6f);
    f[11] = w1 / (h1 + 1e-6f); f[12] = w2 / (h2 + 1e-6f); f[13] = iou;
    f[14] = (c2x > c1x) ? dx : 0.f;  f[15] = (c2x < c1x) ? dx : 0.f;
    f[16] = (c2y > c1y) ? dy : 0.f;  f[17] = (c2y < c1y) ? dy : 0.f;
    unsigned short* o = f36 + (int64_t)li * 64;
#pragma unroll
    for (int i = 0; i < 18; ++i) {
        o[i]      = f2bf(f[i]);
        o[18 + i] = f2bf(logf(f[i] + 1e-6f));
    }
#pragma unroll
    for (int i = 36; i < 64; ++i) o[i] = 0;
}

// ---------------- encoder self-attn: qk = [2048][512] (q|k), v stride 256 ----------------
__global__ __launch_bounds__(128) void enc_attn_k(
    const float* __restrict__ qk, const float* __restrict__ v, float* __restrict__ outp)
{
    int b = blockIdx.x >> 3, hd = blockIdx.x & 7;
    __shared__ float kl[128][32];
    __shared__ float vl[128][32];
    int tid = threadIdx.x;
    for (int i = tid; i < 128 * 32; i += 128) {
        int s = i >> 5, j = i & 31;
        kl[s][j] = qk[((int64_t)(b * 128 + s)) * 512 + 256 + hd * 32 + j];
        vl[s][j] = v[((int64_t)(b * 128 + s)) * 256 + hd * 32 + j];
    }
    __syncthreads();
    int t = tid;
    const float* qp = qk + ((int64_t)(b * 128 + t)) * 512 + hd * 32;
    float qr[32];
#pragma unroll
    for (int j = 0; j < 32; ++j) qr[j] = qp[j] * QSCALE;
    float m = -1e30f, l = 0.f;
    for (int s = 0; s < 128; ++s) {
        float d = 0.f;
#pragma unroll
        for (int j = 0; j < 32; ++j) d += qr[j] * kl[s][j];
        float mn = fmaxf(m, d);
        l = l * __expf(m - mn) + __expf(d - mn);
        m = mn;
    }
    float acc[32] = {};
    for (int s = 0; s < 128; ++s) {
        float d = 0.f;
#pragma unroll
        for (int j = 0; j < 32; ++j) d += qr[j] * kl[s][j];
        float wgt = __expf(d - m);
#pragma unroll
        for (int j = 0; j < 32; ++j) acc[j] += wgt * vl[s][j];
    }
    float linv = 1.f / l;
    float* op = outp + ((int64_t)(b * 128 + t)) * 256 + hd * 32;
#pragma unroll
    for (int j = 0; j < 32; ++j) op[j] = acc[j] * linv;
}

// ---------------- decoder cross-attn: kv = [B*64][512] (k|v), q stride 256 ----------------
__global__ __launch_bounds__(256) void dec_attn_k(
    const float* __restrict__ q, const float* __restrict__ kv,
    float* __restrict__ outp, int rows, int rpb)
{
    int hd = blockIdx.y;
    int r0 = blockIdx.x * 256;
    __shared__ float kl[2][64][32];
    __shared__ float vl[2][64][32];
    int tid = threadIdx.x;
    int b0 = r0 / rpb;
    int b1 = (r0 + 255) / rpb;
    if (b1 >= B) b1 = B - 1;
    for (int i = tid; i < 64 * 32; i += 256) {
        int s = i >> 5, j = i & 31;
        int64_t off0 = ((int64_t)(b0 * MPOSE + s)) * 512 + hd * 32 + j;
        int64_t off1 = ((int64_t)(b1 * MPOSE + s)) * 512 + hd * 32 + j;
        kl[0][s][j] = kv[off0];
        vl[0][s][j] = kv[off0 + 256];
        kl[1][s][j] = kv[off1];
        vl[1][s][j] = kv[off1 + 256];
    }
    __syncthreads();
    int r = r0 + tid;
    if (r >= rows) return;
    int which = (r / rpb == b0) ? 0 : 1;
    int64_t qoff = (int64_t)r * 256 + hd * 32;
    float qr[32];
#pragma unroll
    for (int j = 0; j < 32; ++j) qr[j] = q[qoff + j] * QSCALE;
    float m = -1e30f, l = 0.f;
    for (int s = 0; s < 64; ++s) {
        float d = 0.f;
#pragma unroll
        for (int j = 0; j < 32; ++j) d += qr[j] * kl[which][s][j];
        float mn = fmaxf(m, d);
        l = l * __expf(m - mn) + __expf(d - mn);
        m = mn;
    }
    float acc[32] = {};
    for (int s = 0; s < 64; ++s) {
        float d = 0.f;
#pragma unroll
        for (int j = 0; j < 32; ++j) d += qr[j] * kl[which][s][j];
        float wgt = __expf(d - m);
#pragma unroll
        for (int j = 0; j < 32; ++j) acc[j] += wgt * vl[which][s][j];
    }
    float linv = 1.f / l;
#pragma unroll
    for (int j = 0; j < 32; ++j) outp[qoff + j] = acc[j] * linv;
}

// ---------------- bf16 weight arena offsets (ushort units) ----------------
static constexpr int64_t WT_QKV  = 0;                      // 2 x [768][256]
static constexpr int64_t WT_EOUT = WT_QKV  + 2*196608;     // 2 x [256][256]
static constexpr int64_t WT_EFF1 = WT_EOUT + 2*65536;      // 2 x [1024][256]
static constexpr int64_t WT_EFF2 = WT_EFF1 + 2*262144;     // 2 x [256][1024]
static constexpr int64_t WT_DQ   = WT_EFF2 + 2*262144;     // 2 x [256][256]
static constexpr int64_t WT_DKV  = WT_DQ   + 2*65536;      // 2 x [512][256]
static constexpr int64_t WT_DOUT = WT_DKV  + 2*131072;     // 2 x [256][256]
static constexpr int64_t WT_DFF1 = WT_DOUT + 2*65536;      // 2 x [1024][256]
static constexpr int64_t WT_DFF2 = WT_DFF1 + 2*262144;     // 2 x [256][1024]
static constexpr int64_t WT_SW1  = WT_DFF2 + 2*262144;     // [128][64]
static constexpr int64_t WT_SW2  = WT_SW1 + 8192;          // [256][128]
static constexpr int64_t WT_SW3  = WT_SW2 + 32768;         // [256][256]
static constexpr int64_t WT_BW   = WT_SW3 + 65536;         // [256][512]
static constexpr int64_t WT_PW   = WT_BW  + 131072;        // [256][768]
static constexpr int64_t WT_EPE  = WT_PW  + 196608;        // [256][512]
static constexpr int64_t WT_FC1  = WT_EPE + 131072;        // [512][256] (top|bot)
static constexpr int64_t WT_FC2  = WT_FC1 + 131072;        // [256][256]
static constexpr int64_t WT_M1   = WT_FC2 + 65536;         // [384][512]
static constexpr int64_t WT_M2   = WT_M1  + 196608;        // [256][384]
static constexpr int64_t WT_TOTAL = WT_M2 + 98304;

// ---------------- host orchestration ----------------
extern "C" void kernel_launch(void* const* d_in, const int* in_sizes, int n_in,
                              void* d_out, int out_size, void* d_ws, size_t ws_size,
                              hipStream_t stream)
{
    (void)in_sizes; (void)n_in; (void)out_size;
    const float* boxes     = (const float*)d_in[0];
    const float* embeds    = (const float*)d_in[1];
    const float* sizes     = (const float*)d_in[2];
    const float* pose      = (const float*)d_in[3];
    const float* line      = (const float*)d_in[4];
    const float* sw1 = (const float*)d_in[5];  const float* sb1 = (const float*)d_in[6];
    const float* sw2 = (const float*)d_in[7];  const float* sb2 = (const float*)d_in[8];
    const float* sw3 = (const float*)d_in[9];  const float* sb3 = (const float*)d_in[10];
    const float* bw  = (const float*)d_in[11]; const float* bb  = (const float*)d_in[12];
    const float* pw  = (const float*)d_in[13]; const float* pb  = (const float*)d_in[14];
    const float* lw  = (const float*)d_in[15]; const float* lb  = (const float*)d_in[16];
    const float* enc_pe_w  = (const float*)d_in[17]; const float* enc_pe_b = (const float*)d_in[18];
    const float* enc_qkv_w = (const float*)d_in[19]; const float* enc_qkv_b = (const float*)d_in[20];
    const float* enc_out_w = (const float*)d_in[21]; const float* enc_out_b = (const float*)d_in[22];
    const float* enc_ff1_w = (const float*)d_in[23]; const float* enc_ff1_b = (const float*)d_in[24];
    const float* enc_ff2_w = (const float*)d_in[25]; const float* enc_ff2_b = (const float*)d_in[26];
    const float* enc_ln1_g = (const float*)d_in[27]; const float* enc_ln1_b = (const float*)d_in[28];
    const float* enc_ln2_g = (const float*)d_in[29]; const float* enc_ln2_b = (const float*)d_in[30];
    const float* dec_q_w   = (const float*)d_in[31]; const float* dec_q_b  = (const float*)d_in[32];
    const float* dec_kv_w  = (const float*)d_in[33]; const float* dec_kv_b = (const float*)d_in[34];
    const float* dec_out_w = (const float*)d_in[35]; const float* dec_out_b = (const float*)d_in[36];
    const float* dec_ff1_w = (const float*)d_in[37]; const float* dec_ff1_b = (const float*)d_in[38];
    const float* dec_ff2_w = (const float*)d_in[39]; const float* dec_ff2_b = (const float*)d_in[40];
    const float* dec_ln1_g = (const float*)d_in[41]; const float* dec_ln1_b = (const float*)d_in[42];
    const float* dec_ln2_g = (const float*)d_in[43]; const float* dec_ln2_b = (const float*)d_in[44];
    const float* fc1_w = (const float*)d_in[45]; const float* fc1_b = (const float*)d_in[46];
    const float* fc2_w = (const float*)d_in[47]; const float* fc2_b = (const float*)d_in[48];
    const float* mln1_g = (const float*)d_in[49]; const float* mln1_b = (const float*)d_in[50];
    const float* mln2_g = (const float*)d_in[51]; const float* mln2_b = (const float*)d_in[52];
    const float* m1_w = (const float*)d_in[53]; const float* m1_b = (const float*)d_in[54];
    const float* m2_w = (const float*)d_in[55]; const float* m2_b = (const float*)d_in[56];
    float* out = (float*)d_out;

    // ---- workspace layout ----
    float* base = (float*)d_ws;
    int64_t wsf = (int64_t)(ws_size / sizeof(float));
    float* x_   = base;                       // 524288 (tokens)
    float* bpw_ = x_   + 524288;              // 524288 (pe_tok)
    float* lf   = bpw_ + 524288;              // 4096
    float* kv0  = lf   + 4096;                // 2 x 524288 ([1024][512] k|v per layer; later UV [2048][512])
    unsigned short* wt = (unsigned short*)(kv0 + 2 * 524288);
    float* arena = (float*)(wt + WT_TOTAL);
    const int64_t LIVE_F = arena - base;
    int64_t arena_f = wsf - LIVE_F;
    if (arena_f < 0) arena_f = 0;

    // setup-phase views into arena
    float* posx  = arena;                     // 524288
    float* boxpe = posx  + 524288;            // 1048576
    float* e_qk  = boxpe + 1048576;           // 1048576 ([2048][512] q|k)
    float* e_v   = e_qk  + 1048576;           // 524288
    float* e_t   = e_v   + 524288;            // 524288
    float* e_ff  = e_t   + 524288;            // 2097152
    float* pctx  = e_ff  + 2097152;           // 262144
    float* lm    = pctx  + 262144;            // 32768

    // pair-chunk (bf16): per-row u16 = t1 64 + t3 256 + tsp 256 + zb 512 = 1088
    int64_t rc = ((arena_f * 2) / 1088) & ~127LL;
    if (rc > BP) rc = BP;
    if (rc < 128) rc = 128;

    // ---- stage 0: single-launch weight prep ----
    {
        WTable T;
        int nd = 0, bs = 0;
        auto add = [&](const float* src, int64_t dstOff, int K, int Nn, int Kpad) {
            T.d[nd] = { src, dstOff, K, Nn, Kpad, bs };
            bs += (Kpad / 32) * (Nn / 32);
            ++nd;
        };
        for (int i = 0; i < 2; ++i) {
            add(enc_qkv_w + (int64_t)i*196608, WT_QKV  + i*196608, 256, 768, 256);
            add(enc_out_w + (int64_t)i*65536,  WT_EOUT + i*65536,  256, 256, 256);
            add(enc_ff1_w + (int64_t)i*262144, WT_EFF1 + i*262144, 256, 1024, 256);
            add(enc_ff2_w + (int64_t)i*262144, WT_EFF2 + i*262144, 1024, 256, 1024);
            add(dec_q_w   + (int64_t)i*65536,  WT_DQ   + i*65536,  256, 256, 256);
            add(dec_kv_w  + (int64_t)i*131072, WT_DKV  + i*131072, 256, 512, 256);
            add(dec_out_w + (int64_t)i*65536,  WT_DOUT + i*65536,  256, 256, 256);
            add(dec_ff1_w + (int64_t)i*262144, WT_DFF1 + i*262144, 256, 1024, 256);
            add(dec_ff2_w + (int64_t)i*262144, WT_DFF2 + i*262144, 1024, 256, 1024);
        }
        add(sw1, WT_SW1, 36, 128, 64);
        add(sw2, WT_SW2, 128, 256, 128);
        add(sw3, WT_SW3, 256, 256, 256);
        add(bw,  WT_BW,  512, 256, 512);
        add(pw,  WT_PW,  768, 256, 768);
        add(enc_pe_w, WT_EPE, 512, 256, 512);
        add(fc1_w,             WT_FC1,         256, 256, 256);   // top half -> rows 0..255
        add(fc1_w + 256 * 256, WT_FC1 + 65536, 256, 256, 256);   // bottom -> rows 256..511
        add(fc2_w, WT_FC2, 256, 256, 256);
        add(m1_w, WT_M1, 512, 384, 512);
        add(m2_w, WT_M2, 384, 256, 384);
        T.nDesc = nd;
        wprep_all_k<<<bs, 256, 0, stream>>>(T, wt);
    }

    // ---- stage A: small precomputes ----
    line_mean_k<<<8192, 256, 0, stream>>>(line, lm);
    line_proj_k<<<dim3(8, B), 256, 0, stream>>>(lm, lw, lb, lf);
    boxpe_k<<<(int)BN, 512, 0, stream>>>(boxes, sizes, boxpe);
    bgemm(stream, boxpe, nullptr, 512, wt + WT_EPE, 512, enc_pe_b, posx, 256, (int)BN, 256, 512, false, false);
    bgemm(stream, boxpe, nullptr, 512, wt + WT_BW,  512, bb,       bpw_, 256, (int)BN, 256, 512, false, false);
    bgemm(stream, pose,  nullptr, 768, wt + WT_PW,  768, pb,       pctx, 256, B*MPOSE, 256, 768, false, false);
    for (int l = 0; l < 2; ++l)   // decoder K|V fused per layer
        bgemm(stream, pctx, nullptr, 256, wt + WT_DKV + l*131072, 256, dec_kv_b + (int64_t)l*512,
              kv0 + (int64_t)l*524288, 512, B*MPOSE, 512, 256, false, false);

    // ---- stage B: encoder (2 layers) ----
    hipMemcpyAsync(x_, embeds, BN * 256 * sizeof(float), hipMemcpyDeviceToDevice, stream);
    for (int i = 0; i < 2; ++i) {
        const unsigned short* Wq = wt + WT_QKV + (int64_t)i * 196608;
        const float* bqkv = enc_qkv_b + (int64_t)i * 768;
        bgemm(stream, x_, posx, 256, Wq, 256, bqkv, e_qk, 512, (int)BN, 512, 256, false, false);       // Q|K
        bgemm(stream, x_, nullptr, 256, Wq + 131072, 256, bqkv + 512, e_v, 256, (int)BN, 256, 256, false, false);
        enc_attn_k<<<B * 8, 128, 0, stream>>>(e_qk, e_v, e_t);
        bgemm(stream, e_t, nullptr, 256, wt + WT_EOUT + (int64_t)i*65536, 256, enc_out_b + i * 256,
              e_v, 256, (int)BN, 256, 256, false, false);
        ln_k<<<(int)(BN / 4), 256, 0, stream>>>(x_, x_, e_v, enc_ln1_g + i * 256, enc_ln1_b + i * 256, (int)BN);
        bgemm(stream, x_, nullptr, 256, wt + WT_EFF1 + (int64_t)i*262144, 256, enc_ff1_b + i * 1024,
              e_ff, 1024, (int)BN, 1024, 256, true, false);
        bgemm(stream, e_ff, nullptr, 1024, wt + WT_EFF2 + (int64_t)i*262144, 1024, enc_ff2_b + i * 256,
              e_t, 256, (int)BN, 256, 1024, false, false);
        ln_k<<<(int)(BN / 4), 256, 0, stream>>>(x_, x_, e_t, enc_ln2_g + i * 256, enc_ln2_b + i * 256, (int)BN);
    }

    // ---- stage C: decoder on tokens ----
    add_lf_k<<<(int)BN, 256, 0, stream>>>(bpw_, lf);
    for (int l = 0; l < 2; ++l) {
        bgemm(stream, x_, bpw_, 256, wt + WT_DQ + (int64_t)l*65536, 256, dec_q_b + l * 256,
              e_v, 256, (int)BN, 256, 256, false, false);
        dec_attn_k<<<dim3((int)(BN / 256), 8), 256, 0, stream>>>(e_v, kv0 + (int64_t)l*524288, e_t, (int)BN, N);
        bgemm(stream, e_t, nullptr, 256, wt + WT_DOUT + (int64_t)l*65536, 256, dec_out_b + l * 256,
              e_v, 256, (int)BN, 256, 256, false, false);
        ln_k<<<(int)(BN / 4), 256, 0, stream>>>(x_, x_, e_v, dec_ln1_g + l * 256, dec_ln1_b + l * 256, (int)BN);
        bgemm(stream, x_, nullptr, 256, wt + WT_DFF1 + (int64_t)l*262144, 256, dec_ff1_b + l * 1024,
              e_ff, 1024, (int)BN, 1024, 256, true, false);
        bgemm(stream, e_ff, nullptr, 1024, wt + WT_DFF2 + (int64_t)l*262144, 1024, dec_ff2_b + l * 256,
              e_t, 256, (int)BN, 256, 1024, false, false);
        ln_k<<<(int)(BN / 4), 256, 0, stream>>>(x_, x_, e_t, dec_ln2_g + l * 256, dec_ln2_b + l * 256, (int)BN);
    }
    // U|V = y @ [fc1_top | fc1_bot]  (bias added in pairln)
    float* UV = kv0;                                      // [2048][512]
    bgemm(stream, x_, nullptr, 256, wt + WT_FC1, 256, nullptr, UV, 512, (int)BN, 512, 256, false, false);

    // ---- stage D: per-pair head, chunked, fused 2-stage GEMMs ----
    for (int64_t c0 = 0; c0 < BP; c0 += rc) {
        int rows = (int)((BP - c0 < rc) ? (BP - c0) : rc);   // multiple of 128
        unsigned short* t1  = (unsigned short*)arena;        // rc x 64
        unsigned short* t3  = t1  + (int64_t)rc * 64;        // rc x 256
        unsigned short* tsp = t3  + (int64_t)rc * 256;       // rc x 256
        unsigned short* zb  = tsp + (int64_t)rc * 256;       // rc x 512

        f36_k<<<(rows + 255) / 256, 256, 0, stream>>>(boxes, sizes, t1, (int)c0, rows);
        // t3 = relu( relu(t1@sw1+b1) @ sw2 + b2 )
        fgemm_k<false,true,true><<<rows / 128, 256, 0, stream>>>(
            t1, 64, wt + WT_SW1, 64, sb1, wt + WT_SW2, 128, sb2, t3, 256, 2, 1);
        // tsp = relu(t3@sw3+b3) @ fc2 + fc2_b
        fgemm_k<false,false,true><<<rows / 128, 256, 0, stream>>>(
            t3, 256, wt + WT_SW3, 256, sb3, wt + WT_FC2, 256, fc2_b, tsp, 256, 8, 2);
        lnh_k<<<rows / 4, 256, 0, stream>>>(zb + 256, 512, tsp, 256, mln2_g, mln2_b, rows);
        pairln_k<<<rows / 4, 256, 0, stream>>>(UV, fc1_b, mln1_g, mln1_b, zb, 512, (int)c0, rows);
        // out = relu( relu(relu(z)@m1+m1_b) @ m2 + m2_b )
        fgemm_k<true,true,false><<<rows / 128, 256, 0, stream>>>(
            zb, 512, wt + WT_M1, 512, m1_b, wt + WT_M2, 384, m2_b, out + c0 * 256, 256, 16, 3);
    }
}